// Round 2
// baseline (456.993 us; speedup 1.0000x reference)
//
#include <hip/hip_runtime.h>

// GQA prefill block, MI355X gfx950. Input dtype auto-detected (bf16 vs fp32)
// via cos[0][0]==1.0 bit pattern; all inputs canonicalized to internal bf16.
// Pipeline: qp=x@wq^T, kp=x@wk^T, vp=x@wv^T (MFMA GEMM) -> RMSNorm+RoPE ->
// V transpose -> 1-wave flash attention (16q x 32k tiles, mfma 16x16x32
// bf16) -> out = attn@wo^T (written as bf16 or fp32 per detected dtype).

typedef __bf16 bf16;
typedef __attribute__((ext_vector_type(8))) __bf16 bf16x8;
typedef __attribute__((ext_vector_type(4))) float f32x4;

#define MFMA(a, b, c) __builtin_amdgcn_mfma_f32_16x16x32_bf16((a), (b), (c), 0, 0, 0)

// ---------------------------------------------------------------------------
// dtype detect: cos table row 0 is cos(0)=1.0. bf16 data -> u16[0]=0x3F80;
// fp32 data (little-endian) -> u16[0]=0x0000. flag: 1=bf16, 0=fp32.
// ---------------------------------------------------------------------------
__global__ void detect_kernel(const unsigned short* __restrict__ cosRaw,
                              int* __restrict__ flag) {
  *flag = (cosRaw[0] == 0x3F80) ? 1 : 0;
}

// canonicalize one tensor to bf16 (copy or fp32->bf16 convert)
__global__ __launch_bounds__(256) void convert_kernel(
    const void* __restrict__ in, bf16* __restrict__ out, int n,
    const int* __restrict__ flag) {
  int i = blockIdx.x * 256 + threadIdx.x;
  if (i >= n) return;
  if (*flag) {
    out[i] = ((const bf16*)in)[i];
  } else {
    out[i] = (bf16)((const float*)in)[i];
  }
}

// ---------------------------------------------------------------------------
// Generic C[M,N] = A[M,K] @ W[N,K]^T, bf16 in, fp32 accum.
// 64x64 tile, BK=64, 256 threads (4 waves); wave w does rows 16w..16w+15.
// outflag==nullptr -> bf16 C; else *outflag==0 -> fp32 C, ==1 -> bf16 C.
// ---------------------------------------------------------------------------
__global__ __launch_bounds__(256) void gemm_bt_kernel(
    const bf16* __restrict__ A, const bf16* __restrict__ W,
    void* __restrict__ C, int M, int N, int K,
    const int* __restrict__ outflag) {
  __shared__ bf16 As[64][72];  // +8 pad: 2-way LDS aliasing only (free)
  __shared__ bf16 Bs[64][72];

  const int n0 = blockIdx.x * 64;
  const int m0 = blockIdx.y * 64;
  const int tid = threadIdx.x;
  const int wave = tid >> 6;
  const int lane = tid & 63;
  const int q16 = lane & 15;
  const int quad = lane >> 4;
  const int f32o = outflag ? (*outflag == 0) : 0;

  f32x4 acc[4];
#pragma unroll
  for (int nt = 0; nt < 4; ++nt) acc[nt] = (f32x4){0.f, 0.f, 0.f, 0.f};

  for (int ko = 0; ko < K; ko += 64) {
#pragma unroll
    for (int rep = 0; rep < 2; ++rep) {
      int c = tid + 256 * rep;        // 0..511
      int r = c >> 3;
      int col8 = (c & 7) * 8;
      *(bf16x8*)&As[r][col8] = *(const bf16x8*)&A[(size_t)(m0 + r) * K + ko + col8];
      *(bf16x8*)&Bs[r][col8] = *(const bf16x8*)&W[(size_t)(n0 + r) * K + ko + col8];
    }
    __syncthreads();

    const int mrow = wave * 16 + q16;
    bf16x8 a0 = *(const bf16x8*)&As[mrow][quad * 8];
    bf16x8 a1 = *(const bf16x8*)&As[mrow][32 + quad * 8];
#pragma unroll
    for (int nt = 0; nt < 4; ++nt) {
      bf16x8 b0 = *(const bf16x8*)&Bs[nt * 16 + q16][quad * 8];
      bf16x8 b1 = *(const bf16x8*)&Bs[nt * 16 + q16][32 + quad * 8];
      acc[nt] = MFMA(a0, b0, acc[nt]);
      acc[nt] = MFMA(a1, b1, acc[nt]);
    }
    __syncthreads();
  }

  // C/D layout: col = lane&15, row = quad*4 + reg
#pragma unroll
  for (int nt = 0; nt < 4; ++nt)
#pragma unroll
    for (int r = 0; r < 4; ++r) {
      size_t idx = (size_t)(m0 + wave * 16 + quad * 4 + r) * N + n0 + nt * 16 + q16;
      if (f32o) ((float*)C)[idx] = acc[nt][r];
      else      ((bf16*)C)[idx] = (bf16)acc[nt][r];
    }
}

// ---------------------------------------------------------------------------
// RMSNorm (fp32, over 64 dims) + RoPE, in place. One wave per row of 64.
// rows laid out (b*T+t)*heads + h; outscale folds the 1/8 score scale into q.
// ---------------------------------------------------------------------------
__global__ __launch_bounds__(256) void normrope_kernel(
    bf16* __restrict__ p, const bf16* __restrict__ cosT,
    const bf16* __restrict__ sinT, const bf16* __restrict__ w,
    int heads, float outscale) {
  const int row = blockIdx.x * 4 + (threadIdx.x >> 6);
  const int lane = threadIdx.x & 63;
  const int t = (row / heads) & 2047;  // T = 2048
  bf16* rp = p + (size_t)row * 64;

  float v = (float)rp[lane];
  float ss = v * v;
#pragma unroll
  for (int off = 32; off >= 1; off >>= 1) ss += __shfl_xor(ss, off);
  float r = rsqrtf(ss * (1.0f / 64.0f) + 1e-6f);
  float nv = v * r * (float)w[lane];

  float partner = __shfl_xor(nv, 32);
  int j = lane & 31;
  float c = (float)cosT[t * 32 + j];
  float s = (float)sinT[t * 32 + j];
  float out = (lane < 32) ? (nv * c - partner * s) : (nv * c + partner * s);
  rp[lane] = (bf16)(out * outscale);
}

// ---------------------------------------------------------------------------
// V transpose: (B,T,KV,64) -> (B,KV,64,T). 64x64 tiles through LDS.
// grid = B*KV*(T/64) = 256 blocks of 256 threads.
// ---------------------------------------------------------------------------
__global__ __launch_bounds__(256) void vtrans_kernel(
    const bf16* __restrict__ vp, bf16* __restrict__ vt) {
  __shared__ bf16 tile[64][72];
  const int bz = blockIdx.x;
  const int t0 = (bz & 31) * 64;
  const int kv = (bz >> 5) & 3;
  const int b = bz >> 7;
  const int tid = threadIdx.x;

#pragma unroll
  for (int rep = 0; rep < 2; ++rep) {
    int c = tid + 256 * rep;
    int tl = c >> 3;
    int d8 = (c & 7) * 8;
    *(bf16x8*)&tile[tl][d8] =
        *(const bf16x8*)&vp[(((size_t)(b * 2048 + t0 + tl)) * 4 + kv) * 64 + d8];
  }
  __syncthreads();
#pragma unroll
  for (int rep = 0; rep < 2; ++rep) {
    int c = tid + 256 * rep;
    int d = c >> 3;
    int t8 = (c & 7) * 8;
    bf16x8 pk;
#pragma unroll
    for (int j = 0; j < 8; ++j) pk[j] = tile[t8 + j][d];
    *(bf16x8*)&vt[(((size_t)(b * 4 + kv)) * 64 + d) * 2048 + t0 + t8] = pk;
  }
}

// ---------------------------------------------------------------------------
// Flash attention, causal, GQA (kv head = h/4). One wave per block.
// Q tile = 16 queries, key tiles of 32. Q scale pre-folded (1/8 in normrope).
// qp: (B,T,H,64), kp: (B,T,KV,64), vt: (B,KV,64,T), attn out: (B,T,H,64).
// ---------------------------------------------------------------------------
__global__ __launch_bounds__(64) void flash_kernel(
    const bf16* __restrict__ qp, const bf16* __restrict__ kp,
    const bf16* __restrict__ vt, bf16* __restrict__ attn) {
  const int qt = blockIdx.x;
  const int h = blockIdx.y;
  const int b = blockIdx.z;
  const int kvh = h >> 2;
  const int t0 = qt * 16;
  const int lane = threadIdx.x;
  const int q16 = lane & 15;
  const int quad = lane >> 4;

  __shared__ bf16 Pl[16][40];  // P round-trip: C/D layout -> A layout

  const bf16* qrow = qp + (((size_t)(b * 2048 + t0 + q16)) * 16 + h) * 64;
  bf16x8 qa0 = *(const bf16x8*)(qrow + quad * 8);
  bf16x8 qa1 = *(const bf16x8*)(qrow + 32 + quad * 8);

  float m_r[4], l_r[4];
  f32x4 O[4];
#pragma unroll
  for (int r = 0; r < 4; ++r) { m_r[r] = -1e30f; l_r[r] = 0.f; }
#pragma unroll
  for (int nt = 0; nt < 4; ++nt) O[nt] = (f32x4){0.f, 0.f, 0.f, 0.f};

  const int ntiles = (t0 + 15) / 32 + 1;
  for (int j0 = 0; j0 < ntiles; ++j0) {
    const int kbase = j0 * 32;

    f32x4 s[2];
#pragma unroll
    for (int hlf = 0; hlf < 2; ++hlf) {
      int key = kbase + hlf * 16 + q16;
      const bf16* krow = kp + (((size_t)(b * 2048 + key)) * 4 + kvh) * 64;
      bf16x8 kb0 = *(const bf16x8*)(krow + quad * 8);
      bf16x8 kb1 = *(const bf16x8*)(krow + 32 + quad * 8);
      f32x4 z = (f32x4){0.f, 0.f, 0.f, 0.f};
      z = MFMA(qa0, kb0, z);
      z = MFMA(qa1, kb1, z);
      s[hlf] = z;
    }

    if (kbase + 31 > t0) {
#pragma unroll
      for (int hlf = 0; hlf < 2; ++hlf) {
        int jt = kbase + hlf * 16 + q16;
#pragma unroll
        for (int r = 0; r < 4; ++r)
          if (jt > t0 + quad * 4 + r) s[hlf][r] = -1e30f;
      }
    }

    float mt[4];
#pragma unroll
    for (int r = 0; r < 4; ++r) mt[r] = fmaxf(s[0][r], s[1][r]);
#pragma unroll
    for (int off = 8; off >= 1; off >>= 1)
#pragma unroll
      for (int r = 0; r < 4; ++r) mt[r] = fmaxf(mt[r], __shfl_xor(mt[r], off));

    float al[4];
#pragma unroll
    for (int r = 0; r < 4; ++r) {
      float mn = fmaxf(m_r[r], mt[r]);
      al[r] = __expf(m_r[r] - mn);
      m_r[r] = mn;
    }
#pragma unroll
    for (int hlf = 0; hlf < 2; ++hlf)
#pragma unroll
      for (int r = 0; r < 4; ++r) s[hlf][r] = __expf(s[hlf][r] - m_r[r]);

    float sm[4];
#pragma unroll
    for (int r = 0; r < 4; ++r) sm[r] = s[0][r] + s[1][r];
#pragma unroll
    for (int off = 8; off >= 1; off >>= 1)
#pragma unroll
      for (int r = 0; r < 4; ++r) sm[r] += __shfl_xor(sm[r], off);

#pragma unroll
    for (int r = 0; r < 4; ++r) l_r[r] = l_r[r] * al[r] + sm[r];
#pragma unroll
    for (int nt = 0; nt < 4; ++nt)
#pragma unroll
      for (int r = 0; r < 4; ++r) O[nt][r] *= al[r];

#pragma unroll
    for (int hlf = 0; hlf < 2; ++hlf)
#pragma unroll
      for (int r = 0; r < 4; ++r)
        Pl[quad * 4 + r][hlf * 16 + q16] = (bf16)s[hlf][r];
    __syncthreads();
    bf16x8 pa = *(const bf16x8*)&Pl[q16][quad * 8];
    __syncthreads();

#pragma unroll
    for (int nt = 0; nt < 4; ++nt) {
      const bf16* vrow = vt + (((size_t)(b * 4 + kvh)) * 64 + nt * 16 + q16) * 2048 +
                         kbase + quad * 8;
      bf16x8 vb = *(const bf16x8*)vrow;
      O[nt] = MFMA(pa, vb, O[nt]);
    }
  }

  float inv[4];
#pragma unroll
  for (int r = 0; r < 4; ++r) inv[r] = 1.0f / l_r[r];
#pragma unroll
  for (int nt = 0; nt < 4; ++nt)
#pragma unroll
    for (int r = 0; r < 4; ++r) {
      size_t o = (((size_t)(b * 2048 + t0 + quad * 4 + r)) * 16 + h) * 64 +
                 nt * 16 + q16;
      attn[o] = (bf16)(O[nt][r] * inv[r]);
    }
}

// ---------------------------------------------------------------------------
extern "C" void kernel_launch(void* const* d_in, const int* in_sizes, int n_in,
                              void* d_out, int out_size, void* d_ws, size_t ws_size,
                              hipStream_t stream) {
  // ws layout (bf16 elems)
  bf16* xc  = (bf16*)d_ws;                   // 4096*1024 (aliased as `at` after last use)
  bf16* qp  = xc  + (size_t)4096 * 1024;
  bf16* kp  = qp  + (size_t)4096 * 1024;
  bf16* vp  = kp  + (size_t)4096 * 256;
  bf16* vt  = vp  + (size_t)4096 * 256;
  bf16* wqc = vt  + (size_t)4096 * 256;
  bf16* wkc = wqc + (size_t)1024 * 1024;
  bf16* wvc = wkc + (size_t)256 * 1024;
  bf16* woc = wvc + (size_t)256 * 1024;
  bf16* csc = woc + (size_t)1024 * 1024;
  bf16* snc = csc + (size_t)2048 * 32;
  bf16* qnc = snc + (size_t)2048 * 32;
  bf16* knc = qnc + 64;
  int* flag = (int*)(knc + 64);
  bf16* at  = xc;  // alias: x no longer needed after the three projections

  // 1) dtype detect (cos[0][0] == 1.0 bit pattern)
  detect_kernel<<<1, 1, 0, stream>>>((const unsigned short*)d_in[1], flag);

  // 2) canonicalize all inputs to bf16
  struct { const void* src; bf16* dst; int n; } cv[9] = {
      {d_in[0], xc,  4096 * 1024}, {d_in[1], csc, 2048 * 32},
      {d_in[2], snc, 2048 * 32},   {d_in[3], wqc, 1024 * 1024},
      {d_in[4], wkc, 256 * 1024},  {d_in[5], wvc, 256 * 1024},
      {d_in[6], woc, 1024 * 1024}, {d_in[7], qnc, 64},
      {d_in[8], knc, 64}};
  for (int i = 0; i < 9; ++i)
    convert_kernel<<<(cv[i].n + 255) / 256, 256, 0, stream>>>(cv[i].src, cv[i].dst,
                                                              cv[i].n, flag);

  // 3) projections
  gemm_bt_kernel<<<dim3(16, 64), 256, 0, stream>>>(xc, wqc, qp, 4096, 1024, 1024, nullptr);
  gemm_bt_kernel<<<dim3(4, 64), 256, 0, stream>>>(xc, wkc, kp, 4096, 256, 1024, nullptr);
  gemm_bt_kernel<<<dim3(4, 64), 256, 0, stream>>>(xc, wvc, vp, 4096, 256, 1024, nullptr);

  // 4) q/k RMSNorm + RoPE (q also picks up the 1/8 attention scale)
  normrope_kernel<<<16384, 256, 0, stream>>>(qp, csc, snc, qnc, 16, 0.125f);
  normrope_kernel<<<4096, 256, 0, stream>>>(kp, csc, snc, knc, 4, 1.0f);

  // 5) V -> (B,KV,64,T)
  vtrans_kernel<<<256, 256, 0, stream>>>(vp, vt);

  // 6) causal GQA flash attention (writes at = xc alias)
  flash_kernel<<<dim3(128, 16, 2), 64, 0, stream>>>(qp, kp, vt, at);

  // 7) output projection -> d_out (dtype per flag)
  gemm_bt_kernel<<<dim3(16, 64), 256, 0, stream>>>(at, woc, d_out, 4096, 1024, 1024, flag);
}

// Round 3
// 380.330 us; speedup vs baseline: 1.2016x; 1.2016x over previous
//
#include <hip/hip_runtime.h>

// GQA prefill block, MI355X gfx950. Inputs bf16 (auto-detected vs fp32 via
// cos[0][0] bit pattern; canonicalized to bf16).
// Round 2: flash attention rewritten — 256-thread blocks (4 waves x 16q),
// 64-key K-tiles staged in LDS, per-wave P buffer, reversed causal order.

typedef __bf16 bf16;
typedef __attribute__((ext_vector_type(8))) __bf16 bf16x8;
typedef __attribute__((ext_vector_type(4))) float f32x4;

#define MFMA(a, b, c) __builtin_amdgcn_mfma_f32_16x16x32_bf16((a), (b), (c), 0, 0, 0)

// ---------------------------------------------------------------------------
__global__ void detect_kernel(const unsigned short* __restrict__ cosRaw,
                              int* __restrict__ flag) {
  *flag = (cosRaw[0] == 0x3F80) ? 1 : 0;  // 1=bf16 input, 0=fp32 input
}

__global__ __launch_bounds__(256) void convert_kernel(
    const void* __restrict__ in, bf16* __restrict__ out, int n,
    const int* __restrict__ flag) {
  int i = blockIdx.x * 256 + threadIdx.x;
  if (i >= n) return;
  if (*flag) out[i] = ((const bf16*)in)[i];
  else       out[i] = (bf16)((const float*)in)[i];
}

// ---------------------------------------------------------------------------
// C[M,N] = A[M,K] @ W[N,K]^T, bf16 in, fp32 accum. 64x64 tile, BK=64.
// ---------------------------------------------------------------------------
__global__ __launch_bounds__(256) void gemm_bt_kernel(
    const bf16* __restrict__ A, const bf16* __restrict__ W,
    void* __restrict__ C, int M, int N, int K,
    const int* __restrict__ outflag) {
  __shared__ bf16 As[64][72];
  __shared__ bf16 Bs[64][72];

  const int n0 = blockIdx.x * 64;
  const int m0 = blockIdx.y * 64;
  const int tid = threadIdx.x;
  const int wave = tid >> 6;
  const int lane = tid & 63;
  const int q16 = lane & 15;
  const int quad = lane >> 4;
  const int f32o = outflag ? (*outflag == 0) : 0;

  f32x4 acc[4];
#pragma unroll
  for (int nt = 0; nt < 4; ++nt) acc[nt] = (f32x4){0.f, 0.f, 0.f, 0.f};

  for (int ko = 0; ko < K; ko += 64) {
#pragma unroll
    for (int rep = 0; rep < 2; ++rep) {
      int c = tid + 256 * rep;
      int r = c >> 3;
      int col8 = (c & 7) * 8;
      *(bf16x8*)&As[r][col8] = *(const bf16x8*)&A[(size_t)(m0 + r) * K + ko + col8];
      *(bf16x8*)&Bs[r][col8] = *(const bf16x8*)&W[(size_t)(n0 + r) * K + ko + col8];
    }
    __syncthreads();

    const int mrow = wave * 16 + q16;
    bf16x8 a0 = *(const bf16x8*)&As[mrow][quad * 8];
    bf16x8 a1 = *(const bf16x8*)&As[mrow][32 + quad * 8];
#pragma unroll
    for (int nt = 0; nt < 4; ++nt) {
      bf16x8 b0 = *(const bf16x8*)&Bs[nt * 16 + q16][quad * 8];
      bf16x8 b1 = *(const bf16x8*)&Bs[nt * 16 + q16][32 + quad * 8];
      acc[nt] = MFMA(a0, b0, acc[nt]);
      acc[nt] = MFMA(a1, b1, acc[nt]);
    }
    __syncthreads();
  }

#pragma unroll
  for (int nt = 0; nt < 4; ++nt)
#pragma unroll
    for (int r = 0; r < 4; ++r) {
      size_t idx = (size_t)(m0 + wave * 16 + quad * 4 + r) * N + n0 + nt * 16 + q16;
      if (f32o) ((float*)C)[idx] = acc[nt][r];
      else      ((bf16*)C)[idx] = (bf16)acc[nt][r];
    }
}

// ---------------------------------------------------------------------------
// RMSNorm + RoPE, in place. One wave per 64-dim row.
// ---------------------------------------------------------------------------
__global__ __launch_bounds__(256) void normrope_kernel(
    bf16* __restrict__ p, const bf16* __restrict__ cosT,
    const bf16* __restrict__ sinT, const bf16* __restrict__ w,
    int heads, float outscale) {
  const int row = blockIdx.x * 4 + (threadIdx.x >> 6);
  const int lane = threadIdx.x & 63;
  const int t = (row / heads) & 2047;
  bf16* rp = p + (size_t)row * 64;

  float v = (float)rp[lane];
  float ss = v * v;
#pragma unroll
  for (int off = 32; off >= 1; off >>= 1) ss += __shfl_xor(ss, off);
  float r = rsqrtf(ss * (1.0f / 64.0f) + 1e-6f);
  float nv = v * r * (float)w[lane];

  float partner = __shfl_xor(nv, 32);
  int j = lane & 31;
  float c = (float)cosT[t * 32 + j];
  float s = (float)sinT[t * 32 + j];
  float out = (lane < 32) ? (nv * c - partner * s) : (nv * c + partner * s);
  rp[lane] = (bf16)(out * outscale);
}

// ---------------------------------------------------------------------------
// V transpose: (B,T,KV,64) -> (B,KV,64,T).
// ---------------------------------------------------------------------------
__global__ __launch_bounds__(256) void vtrans_kernel(
    const bf16* __restrict__ vp, bf16* __restrict__ vt) {
  __shared__ bf16 tile[64][72];
  const int bz = blockIdx.x;
  const int t0 = (bz & 31) * 64;
  const int kv = (bz >> 5) & 3;
  const int b = bz >> 7;
  const int tid = threadIdx.x;

#pragma unroll
  for (int rep = 0; rep < 2; ++rep) {
    int c = tid + 256 * rep;
    int tl = c >> 3;
    int d8 = (c & 7) * 8;
    *(bf16x8*)&tile[tl][d8] =
        *(const bf16x8*)&vp[(((size_t)(b * 2048 + t0 + tl)) * 4 + kv) * 64 + d8];
  }
  __syncthreads();
#pragma unroll
  for (int rep = 0; rep < 2; ++rep) {
    int c = tid + 256 * rep;
    int d = c >> 3;
    int t8 = (c & 7) * 8;
    bf16x8 pk;
#pragma unroll
    for (int j = 0; j < 8; ++j) pk[j] = tile[t8 + j][d];
    *(bf16x8*)&vt[(((size_t)(b * 4 + kv)) * 64 + d) * 2048 + t0 + t8] = pk;
  }
}

// ---------------------------------------------------------------------------
// Flash attention v2: 256-thread block = 4 waves; block covers 64 queries
// (wave w owns queries qblk*64 + 16w ..+15). K staged in LDS 64 keys/tile.
// qblk reversed so heavy causal blocks launch first.
// qp: (B,T,H,64) (pre-scaled by 1/8), kp: (B,T,KV,64), vt: (B,KV,64,T).
// ---------------------------------------------------------------------------
__global__ __launch_bounds__(256) void flash_kernel(
    const bf16* __restrict__ qp, const bf16* __restrict__ kp,
    const bf16* __restrict__ vt, bf16* __restrict__ attn) {
  const int qblk = (int)gridDim.x - 1 - (int)blockIdx.x;
  const int h = blockIdx.y;
  const int b = blockIdx.z;
  const int kvh = h >> 2;
  const int tid = threadIdx.x;
  const int wave = tid >> 6;
  const int lane = tid & 63;
  const int q16 = lane & 15;
  const int quad = lane >> 4;
  const int t0 = qblk * 64 + wave * 16;  // this wave's first query

  __shared__ bf16 Ks[64][72];       // 144B row stride: 16B-aligned, even banks
  __shared__ bf16 Pl[4][16][72];    // per-wave P (C/D -> A layout roundtrip)

  const bf16* qrow = qp + (((size_t)(b * 2048 + t0 + q16)) * 16 + h) * 64;
  bf16x8 qa0 = *(const bf16x8*)(qrow + quad * 8);
  bf16x8 qa1 = *(const bf16x8*)(qrow + 32 + quad * 8);

  float m_r[4], l_r[4];
  f32x4 O[4];
#pragma unroll
  for (int r = 0; r < 4; ++r) { m_r[r] = -1e30f; l_r[r] = 0.f; }
#pragma unroll
  for (int nt = 0; nt < 4; ++nt) O[nt] = (f32x4){0.f, 0.f, 0.f, 0.f};

  const int kend = qblk * 64 + 64;
  for (int kbase = 0; kbase < kend; kbase += 64) {
    // stage K tile (64 keys x 64 dims), all 4 waves cooperatively
#pragma unroll
    for (int rep = 0; rep < 2; ++rep) {
      int c = tid + 256 * rep;
      int key = c >> 3;
      int d8 = (c & 7) * 8;
      *(bf16x8*)&Ks[key][d8] =
          *(const bf16x8*)&kp[(((size_t)(b * 2048 + kbase + key)) * 4 + kvh) * 64 + d8];
    }
    __syncthreads();

    // S = Q K^T : 4 key subtiles of 16
    f32x4 s[4];
#pragma unroll
    for (int kt = 0; kt < 4; ++kt) {
      bf16x8 kb0 = *(const bf16x8*)&Ks[kt * 16 + q16][quad * 8];
      bf16x8 kb1 = *(const bf16x8*)&Ks[kt * 16 + q16][32 + quad * 8];
      f32x4 z = (f32x4){0.f, 0.f, 0.f, 0.f};
      z = MFMA(qa0, kb0, z);
      z = MFMA(qa1, kb1, z);
      s[kt] = z;
    }

    // causal mask (wave-uniform branch; only diagonal-straddling tiles)
    if (kbase + 63 > t0) {
#pragma unroll
      for (int kt = 0; kt < 4; ++kt) {
        int jt = kbase + kt * 16 + q16;
#pragma unroll
        for (int r = 0; r < 4; ++r)
          if (jt > t0 + quad * 4 + r) s[kt][r] = -1e30f;
      }
    }

    // online softmax over 64 keys (rows live across 16 lanes)
    float mt[4];
#pragma unroll
    for (int r = 0; r < 4; ++r)
      mt[r] = fmaxf(fmaxf(s[0][r], s[1][r]), fmaxf(s[2][r], s[3][r]));
#pragma unroll
    for (int off = 8; off >= 1; off >>= 1)
#pragma unroll
      for (int r = 0; r < 4; ++r) mt[r] = fmaxf(mt[r], __shfl_xor(mt[r], off));

    float al[4];
#pragma unroll
    for (int r = 0; r < 4; ++r) {
      float mn = fmaxf(m_r[r], mt[r]);
      al[r] = __expf(m_r[r] - mn);
      m_r[r] = mn;
    }
#pragma unroll
    for (int kt = 0; kt < 4; ++kt)
#pragma unroll
      for (int r = 0; r < 4; ++r) s[kt][r] = __expf(s[kt][r] - m_r[r]);

    float sm[4];
#pragma unroll
    for (int r = 0; r < 4; ++r)
      sm[r] = (s[0][r] + s[1][r]) + (s[2][r] + s[3][r]);
#pragma unroll
    for (int off = 8; off >= 1; off >>= 1)
#pragma unroll
      for (int r = 0; r < 4; ++r) sm[r] += __shfl_xor(sm[r], off);

#pragma unroll
    for (int r = 0; r < 4; ++r) l_r[r] = l_r[r] * al[r] + sm[r];
#pragma unroll
    for (int nt = 0; nt < 4; ++nt)
#pragma unroll
      for (int r = 0; r < 4; ++r) O[nt][r] *= al[r];

    // P -> per-wave LDS (C/D layout in, A layout out); wave-internal only,
    // no __syncthreads needed (lgkmcnt ordering within the wave).
#pragma unroll
    for (int kt = 0; kt < 4; ++kt)
#pragma unroll
      for (int r = 0; r < 4; ++r)
        Pl[wave][quad * 4 + r][kt * 16 + q16] = (bf16)s[kt][r];

    // O += P V over two 32-key halves
#pragma unroll
    for (int kh = 0; kh < 2; ++kh) {
      bf16x8 pa = *(const bf16x8*)&Pl[wave][q16][kh * 32 + quad * 8];
#pragma unroll
      for (int nt = 0; nt < 4; ++nt) {
        const bf16* vrow = vt +
            (((size_t)(b * 4 + kvh)) * 64 + nt * 16 + q16) * 2048 +
            kbase + kh * 32 + quad * 8;
        bf16x8 vb = *(const bf16x8*)vrow;
        O[nt] = MFMA(pa, vb, O[nt]);
      }
    }
    __syncthreads();  // all waves done with Ks before next staging
  }

  float inv[4];
#pragma unroll
  for (int r = 0; r < 4; ++r) inv[r] = 1.0f / l_r[r];
#pragma unroll
  for (int nt = 0; nt < 4; ++nt)
#pragma unroll
    for (int r = 0; r < 4; ++r) {
      size_t o = (((size_t)(b * 2048 + t0 + quad * 4 + r)) * 16 + h) * 64 +
                 nt * 16 + q16;
      attn[o] = (bf16)(O[nt][r] * inv[r]);
    }
}

// ---------------------------------------------------------------------------
extern "C" void kernel_launch(void* const* d_in, const int* in_sizes, int n_in,
                              void* d_out, int out_size, void* d_ws, size_t ws_size,
                              hipStream_t stream) {
  bf16* xc  = (bf16*)d_ws;                   // aliased as `at` after last use
  bf16* qp  = xc  + (size_t)4096 * 1024;
  bf16* kp  = qp  + (size_t)4096 * 1024;
  bf16* vp  = kp  + (size_t)4096 * 256;
  bf16* vt  = vp  + (size_t)4096 * 256;
  bf16* wqc = vt  + (size_t)4096 * 256;
  bf16* wkc = wqc + (size_t)1024 * 1024;
  bf16* wvc = wkc + (size_t)256 * 1024;
  bf16* woc = wvc + (size_t)256 * 1024;
  bf16* csc = woc + (size_t)1024 * 1024;
  bf16* snc = csc + (size_t)2048 * 32;
  bf16* qnc = snc + (size_t)2048 * 32;
  bf16* knc = qnc + 64;
  int* flag = (int*)(knc + 64);
  bf16* at  = xc;

  detect_kernel<<<1, 1, 0, stream>>>((const unsigned short*)d_in[1], flag);

  struct { const void* src; bf16* dst; int n; } cv[9] = {
      {d_in[0], xc,  4096 * 1024}, {d_in[1], csc, 2048 * 32},
      {d_in[2], snc, 2048 * 32},   {d_in[3], wqc, 1024 * 1024},
      {d_in[4], wkc, 256 * 1024},  {d_in[5], wvc, 256 * 1024},
      {d_in[6], woc, 1024 * 1024}, {d_in[7], qnc, 64},
      {d_in[8], knc, 64}};
  for (int i = 0; i < 9; ++i)
    convert_kernel<<<(cv[i].n + 255) / 256, 256, 0, stream>>>(cv[i].src, cv[i].dst,
                                                              cv[i].n, flag);

  gemm_bt_kernel<<<dim3(16, 64), 256, 0, stream>>>(xc, wqc, qp, 4096, 1024, 1024, nullptr);
  gemm_bt_kernel<<<dim3(4, 64), 256, 0, stream>>>(xc, wkc, kp, 4096, 256, 1024, nullptr);
  gemm_bt_kernel<<<dim3(4, 64), 256, 0, stream>>>(xc, wvc, vp, 4096, 256, 1024, nullptr);

  normrope_kernel<<<16384, 256, 0, stream>>>(qp, csc, snc, qnc, 16, 0.125f);
  normrope_kernel<<<4096, 256, 0, stream>>>(kp, csc, snc, knc, 4, 1.0f);

  vtrans_kernel<<<256, 256, 0, stream>>>(vp, vt);

  // flash v2: grid (32 qblks, 16 h, 2 b), 256 threads
  flash_kernel<<<dim3(32, 16, 2), 256, 0, stream>>>(qp, kp, vt, at);

  gemm_bt_kernel<<<dim3(16, 64), 256, 0, stream>>>(at, woc, d_out, 4096, 1024, 1024, flag);
}

// Round 4
// 354.423 us; speedup vs baseline: 1.2894x; 1.0731x over previous
//
#include <hip/hip_runtime.h>

// GQA prefill block, MI355X gfx950. Inputs bf16 (auto-detected vs fp32 via
// cos[0][0] bit pattern; canonicalized to bf16).
// Round 3: flash K-loop software-pipelined — double-buffered K staging via
// global_load_lds(16B) with XOR bank swizzle, early V loads, 4 waves/SIMD.

typedef __bf16 bf16;
typedef __attribute__((ext_vector_type(8))) __bf16 bf16x8;
typedef __attribute__((ext_vector_type(4))) float f32x4;

#define MFMA(a, b, c) __builtin_amdgcn_mfma_f32_16x16x32_bf16((a), (b), (c), 0, 0, 0)
#define GLOAD_LDS16(g, l)                                        \
  __builtin_amdgcn_global_load_lds(                              \
      (const __attribute__((address_space(1))) void*)(g),        \
      (__attribute__((address_space(3))) void*)(l), 16, 0, 0)

// ---------------------------------------------------------------------------
__global__ void detect_kernel(const unsigned short* __restrict__ cosRaw,
                              int* __restrict__ flag) {
  *flag = (cosRaw[0] == 0x3F80) ? 1 : 0;  // 1=bf16 input, 0=fp32 input
}

__global__ __launch_bounds__(256) void convert_kernel(
    const void* __restrict__ in, bf16* __restrict__ out, int n,
    const int* __restrict__ flag) {
  int i = blockIdx.x * 256 + threadIdx.x;
  if (i >= n) return;
  if (*flag) out[i] = ((const bf16*)in)[i];
  else       out[i] = (bf16)((const float*)in)[i];
}

// ---------------------------------------------------------------------------
// C[M,N] = A[M,K] @ W[N,K]^T, bf16 in, fp32 accum. 64x64 tile, BK=64.
// ---------------------------------------------------------------------------
__global__ __launch_bounds__(256) void gemm_bt_kernel(
    const bf16* __restrict__ A, const bf16* __restrict__ W,
    void* __restrict__ C, int M, int N, int K,
    const int* __restrict__ outflag) {
  __shared__ bf16 As[64][72];
  __shared__ bf16 Bs[64][72];

  const int n0 = blockIdx.x * 64;
  const int m0 = blockIdx.y * 64;
  const int tid = threadIdx.x;
  const int wave = tid >> 6;
  const int lane = tid & 63;
  const int q16 = lane & 15;
  const int quad = lane >> 4;
  const int f32o = outflag ? (*outflag == 0) : 0;

  f32x4 acc[4];
#pragma unroll
  for (int nt = 0; nt < 4; ++nt) acc[nt] = (f32x4){0.f, 0.f, 0.f, 0.f};

  for (int ko = 0; ko < K; ko += 64) {
#pragma unroll
    for (int rep = 0; rep < 2; ++rep) {
      int c = tid + 256 * rep;
      int r = c >> 3;
      int col8 = (c & 7) * 8;
      *(bf16x8*)&As[r][col8] = *(const bf16x8*)&A[(size_t)(m0 + r) * K + ko + col8];
      *(bf16x8*)&Bs[r][col8] = *(const bf16x8*)&W[(size_t)(n0 + r) * K + ko + col8];
    }
    __syncthreads();

    const int mrow = wave * 16 + q16;
    bf16x8 a0 = *(const bf16x8*)&As[mrow][quad * 8];
    bf16x8 a1 = *(const bf16x8*)&As[mrow][32 + quad * 8];
#pragma unroll
    for (int nt = 0; nt < 4; ++nt) {
      bf16x8 b0 = *(const bf16x8*)&Bs[nt * 16 + q16][quad * 8];
      bf16x8 b1 = *(const bf16x8*)&Bs[nt * 16 + q16][32 + quad * 8];
      acc[nt] = MFMA(a0, b0, acc[nt]);
      acc[nt] = MFMA(a1, b1, acc[nt]);
    }
    __syncthreads();
  }

#pragma unroll
  for (int nt = 0; nt < 4; ++nt)
#pragma unroll
    for (int r = 0; r < 4; ++r) {
      size_t idx = (size_t)(m0 + wave * 16 + quad * 4 + r) * N + n0 + nt * 16 + q16;
      if (f32o) ((float*)C)[idx] = acc[nt][r];
      else      ((bf16*)C)[idx] = (bf16)acc[nt][r];
    }
}

// ---------------------------------------------------------------------------
// RMSNorm + RoPE, in place. One wave per 64-dim row.
// ---------------------------------------------------------------------------
__global__ __launch_bounds__(256) void normrope_kernel(
    bf16* __restrict__ p, const bf16* __restrict__ cosT,
    const bf16* __restrict__ sinT, const bf16* __restrict__ w,
    int heads, float outscale) {
  const int row = blockIdx.x * 4 + (threadIdx.x >> 6);
  const int lane = threadIdx.x & 63;
  const int t = (row / heads) & 2047;
  bf16* rp = p + (size_t)row * 64;

  float v = (float)rp[lane];
  float ss = v * v;
#pragma unroll
  for (int off = 32; off >= 1; off >>= 1) ss += __shfl_xor(ss, off);
  float r = rsqrtf(ss * (1.0f / 64.0f) + 1e-6f);
  float nv = v * r * (float)w[lane];

  float partner = __shfl_xor(nv, 32);
  int j = lane & 31;
  float c = (float)cosT[t * 32 + j];
  float s = (float)sinT[t * 32 + j];
  float out = (lane < 32) ? (nv * c - partner * s) : (nv * c + partner * s);
  rp[lane] = (bf16)(out * outscale);
}

// ---------------------------------------------------------------------------
// V transpose: (B,T,KV,64) -> (B,KV,64,T).
// ---------------------------------------------------------------------------
__global__ __launch_bounds__(256) void vtrans_kernel(
    const bf16* __restrict__ vp, bf16* __restrict__ vt) {
  __shared__ bf16 tile[64][72];
  const int bz = blockIdx.x;
  const int t0 = (bz & 31) * 64;
  const int kv = (bz >> 5) & 3;
  const int b = bz >> 7;
  const int tid = threadIdx.x;

#pragma unroll
  for (int rep = 0; rep < 2; ++rep) {
    int c = tid + 256 * rep;
    int tl = c >> 3;
    int d8 = (c & 7) * 8;
    *(bf16x8*)&tile[tl][d8] =
        *(const bf16x8*)&vp[(((size_t)(b * 2048 + t0 + tl)) * 4 + kv) * 64 + d8];
  }
  __syncthreads();
#pragma unroll
  for (int rep = 0; rep < 2; ++rep) {
    int c = tid + 256 * rep;
    int d = c >> 3;
    int t8 = (c & 7) * 8;
    bf16x8 pk;
#pragma unroll
    for (int j = 0; j < 8; ++j) pk[j] = tile[t8 + j][d];
    *(bf16x8*)&vt[(((size_t)(b * 4 + kv)) * 64 + d) * 2048 + t0 + t8] = pk;
  }
}

// ---------------------------------------------------------------------------
// Flash attention v3: 256-thread block = 4 waves; block covers 64 queries.
// Double-buffered K staging via global_load_lds (wave-uniform base + lane*16,
// so Ks is flat [64][64] with chunk c of key k stored at position c^(k&7) —
// XOR swizzle keeps b128 reads at the 8-cycle bank floor).
// qp: (B,T,H,64) pre-scaled 1/8, kp: (B,T,KV,64), vt: (B,KV,64,T).
// ---------------------------------------------------------------------------
__global__ __launch_bounds__(256, 4) void flash_kernel(
    const bf16* __restrict__ qp, const bf16* __restrict__ kp,
    const bf16* __restrict__ vt, bf16* __restrict__ attn) {
  const int qblk = (int)gridDim.x - 1 - (int)blockIdx.x;  // heavy blocks first
  const int h = blockIdx.y;
  const int b = blockIdx.z;
  const int kvh = h >> 2;
  const int tid = threadIdx.x;
  const int wave = tid >> 6;
  const int lane = tid & 63;
  const int q16 = lane & 15;
  const int quad = lane >> 4;
  const int t0 = qblk * 64 + wave * 16;

  __shared__ bf16 Ks[2][64 * 64];   // dbuf, swizzled
  __shared__ bf16 Pl[4][16][72];    // per-wave P roundtrip

  const bf16* qrow = qp + (((size_t)(b * 2048 + t0 + q16)) * 16 + h) * 64;
  bf16x8 qa0 = *(const bf16x8*)(qrow + quad * 8);
  bf16x8 qa1 = *(const bf16x8*)(qrow + 32 + quad * 8);

  float m_r[4], l_r[4];
  f32x4 O[4];
#pragma unroll
  for (int r = 0; r < 4; ++r) { m_r[r] = -1e30f; l_r[r] = 0.f; }
#pragma unroll
  for (int nt = 0; nt < 4; ++nt) O[nt] = (f32x4){0.f, 0.f, 0.f, 0.f};

  const int ntile = qblk + 1;

  // issue-only staging of K tile tk into buffer bb (no waits here)
  auto stage = [&](int tk, int bb) {
#pragma unroll
    for (int r = 0; r < 2; ++r) {
      int s2 = wave * 2 + r;             // 8-key segment id, wave-uniform
      int k = s2 * 8 + (lane >> 3);
      int c = (lane & 7) ^ (k & 7);      // swizzled data chunk for this slot
      const bf16* g =
          &kp[(((size_t)(b * 2048 + tk * 64 + k)) * 4 + kvh) * 64 + c * 8];
      GLOAD_LDS16(g, &Ks[bb][s2 * 512]); // + lane*16 by HW
    }
  };

  stage(0, 0);

  for (int t = 0; t < ntile; ++t) {
    const int bb = t & 1;
    const int kbase = t * 64;
    __syncthreads();  // drains vmcnt: buffer bb staged; prev-iter reads closed
    if (t + 1 < ntile) stage(t + 1, bb ^ 1);

    // early V loads — independent of softmax, consumed by PV MFMAs
    bf16x8 vb[2][4];
#pragma unroll
    for (int kh = 0; kh < 2; ++kh)
#pragma unroll
      for (int nt = 0; nt < 4; ++nt)
        vb[kh][nt] = *(const bf16x8*)&vt[
            ((size_t)(b * 4 + kvh) * 64 + nt * 16 + q16) * 2048 +
            kbase + kh * 32 + quad * 8];

    // S = Q K^T : 4 key subtiles of 16 (swizzled Ks reads)
    f32x4 s[4];
#pragma unroll
    for (int kt = 0; kt < 4; ++kt) {
      int rr = kt * 16 + q16;
      int r7 = q16 & 7;
      bf16x8 kb0 = *(const bf16x8*)&Ks[bb][rr * 64 + ((quad ^ r7) * 8)];
      bf16x8 kb1 = *(const bf16x8*)&Ks[bb][rr * 64 + (((quad + 4) ^ r7) * 8)];
      f32x4 z = (f32x4){0.f, 0.f, 0.f, 0.f};
      z = MFMA(qa0, kb0, z);
      z = MFMA(qa1, kb1, z);
      s[kt] = z;
    }

    // causal mask (wave-uniform branch)
    if (kbase + 63 > t0) {
#pragma unroll
      for (int kt = 0; kt < 4; ++kt) {
        int jt = kbase + kt * 16 + q16;
#pragma unroll
        for (int r = 0; r < 4; ++r)
          if (jt > t0 + quad * 4 + r) s[kt][r] = -1e30f;
      }
    }

    // online softmax over 64 keys
    float mt[4];
#pragma unroll
    for (int r = 0; r < 4; ++r)
      mt[r] = fmaxf(fmaxf(s[0][r], s[1][r]), fmaxf(s[2][r], s[3][r]));
#pragma unroll
    for (int off = 8; off >= 1; off >>= 1)
#pragma unroll
      for (int r = 0; r < 4; ++r) mt[r] = fmaxf(mt[r], __shfl_xor(mt[r], off));

    float al[4];
#pragma unroll
    for (int r = 0; r < 4; ++r) {
      float mn = fmaxf(m_r[r], mt[r]);
      al[r] = __expf(m_r[r] - mn);
      m_r[r] = mn;
    }
#pragma unroll
    for (int kt = 0; kt < 4; ++kt)
#pragma unroll
      for (int r = 0; r < 4; ++r) s[kt][r] = __expf(s[kt][r] - m_r[r]);

    float sm[4];
#pragma unroll
    for (int r = 0; r < 4; ++r)
      sm[r] = (s[0][r] + s[1][r]) + (s[2][r] + s[3][r]);
#pragma unroll
    for (int off = 8; off >= 1; off >>= 1)
#pragma unroll
      for (int r = 0; r < 4; ++r) sm[r] += __shfl_xor(sm[r], off);

#pragma unroll
    for (int r = 0; r < 4; ++r) l_r[r] = l_r[r] * al[r] + sm[r];
#pragma unroll
    for (int nt = 0; nt < 4; ++nt)
#pragma unroll
      for (int r = 0; r < 4; ++r) O[nt][r] *= al[r];

    // P: C/D layout -> per-wave LDS -> A layout (wave-internal, no barrier)
#pragma unroll
    for (int kt = 0; kt < 4; ++kt)
#pragma unroll
      for (int r = 0; r < 4; ++r)
        Pl[wave][quad * 4 + r][kt * 16 + q16] = (bf16)s[kt][r];

#pragma unroll
    for (int kh = 0; kh < 2; ++kh) {
      bf16x8 pa = *(const bf16x8*)&Pl[wave][q16][kh * 32 + quad * 8];
#pragma unroll
      for (int nt = 0; nt < 4; ++nt) O[nt] = MFMA(pa, vb[kh][nt], O[nt]);
    }
  }

  float inv[4];
#pragma unroll
  for (int r = 0; r < 4; ++r) inv[r] = 1.0f / l_r[r];
#pragma unroll
  for (int nt = 0; nt < 4; ++nt)
#pragma unroll
    for (int r = 0; r < 4; ++r) {
      size_t o = (((size_t)(b * 2048 + t0 + quad * 4 + r)) * 16 + h) * 64 +
                 nt * 16 + q16;
      attn[o] = (bf16)(O[nt][r] * inv[r]);
    }
}

// ---------------------------------------------------------------------------
extern "C" void kernel_launch(void* const* d_in, const int* in_sizes, int n_in,
                              void* d_out, int out_size, void* d_ws, size_t ws_size,
                              hipStream_t stream) {
  bf16* xc  = (bf16*)d_ws;                   // aliased as `at` after last use
  bf16* qp  = xc  + (size_t)4096 * 1024;
  bf16* kp  = qp  + (size_t)4096 * 1024;
  bf16* vp  = kp  + (size_t)4096 * 256;
  bf16* vt  = vp  + (size_t)4096 * 256;
  bf16* wqc = vt  + (size_t)4096 * 256;
  bf16* wkc = wqc + (size_t)1024 * 1024;
  bf16* wvc = wkc + (size_t)256 * 1024;
  bf16* woc = wvc + (size_t)256 * 1024;
  bf16* csc = woc + (size_t)1024 * 1024;
  bf16* snc = csc + (size_t)2048 * 32;
  bf16* qnc = snc + (size_t)2048 * 32;
  bf16* knc = qnc + 64;
  int* flag = (int*)(knc + 64);
  bf16* at  = xc;

  detect_kernel<<<1, 1, 0, stream>>>((const unsigned short*)d_in[1], flag);

  struct { const void* src; bf16* dst; int n; } cv[9] = {
      {d_in[0], xc,  4096 * 1024}, {d_in[1], csc, 2048 * 32},
      {d_in[2], snc, 2048 * 32},   {d_in[3], wqc, 1024 * 1024},
      {d_in[4], wkc, 256 * 1024},  {d_in[5], wvc, 256 * 1024},
      {d_in[6], woc, 1024 * 1024}, {d_in[7], qnc, 64},
      {d_in[8], knc, 64}};
  for (int i = 0; i < 9; ++i)
    convert_kernel<<<(cv[i].n + 255) / 256, 256, 0, stream>>>(cv[i].src, cv[i].dst,
                                                              cv[i].n, flag);

  gemm_bt_kernel<<<dim3(16, 64), 256, 0, stream>>>(xc, wqc, qp, 4096, 1024, 1024, nullptr);
  gemm_bt_kernel<<<dim3(4, 64), 256, 0, stream>>>(xc, wkc, kp, 4096, 256, 1024, nullptr);
  gemm_bt_kernel<<<dim3(4, 64), 256, 0, stream>>>(xc, wvc, vp, 4096, 256, 1024, nullptr);

  normrope_kernel<<<16384, 256, 0, stream>>>(qp, csc, snc, qnc, 16, 0.125f);
  normrope_kernel<<<4096, 256, 0, stream>>>(kp, csc, snc, knc, 4, 1.0f);

  vtrans_kernel<<<256, 256, 0, stream>>>(vp, vt);

  flash_kernel<<<dim3(32, 16, 2), 256, 0, stream>>>(qp, kp, vt, at);

  gemm_bt_kernel<<<dim3(16, 64), 256, 0, stream>>>(at, woc, d_out, 4096, 1024, 1024, flag);
}

// Round 5
// 285.869 us; speedup vs baseline: 1.5986x; 1.2398x over previous
//
#include <hip/hip_runtime.h>

// GQA prefill block, MI355X gfx950. Inputs bf16 (auto-detected vs fp32 via
// cos[0][0] bit pattern; canonicalized to bf16).
// Round 4: flash v4 — fixed-max softmax (|S|<=8 after RMSNorm, use exp(S-9)),
// l via ones-MFMA, K+V double-buffered in LDS via register staging (single
// barrier/tile), XOR-swizzled conflict-free LDS layouts.

typedef __bf16 bf16;
typedef __attribute__((ext_vector_type(8))) __bf16 bf16x8;
typedef __attribute__((ext_vector_type(4))) float f32x4;

#define MFMA(a, b, c) __builtin_amdgcn_mfma_f32_16x16x32_bf16((a), (b), (c), 0, 0, 0)

// ---------------------------------------------------------------------------
__global__ void detect_kernel(const unsigned short* __restrict__ cosRaw,
                              int* __restrict__ flag) {
  *flag = (cosRaw[0] == 0x3F80) ? 1 : 0;  // 1=bf16 input, 0=fp32 input
}

__global__ __launch_bounds__(256) void convert_kernel(
    const void* __restrict__ in, bf16* __restrict__ out, int n,
    const int* __restrict__ flag) {
  int i = blockIdx.x * 256 + threadIdx.x;
  if (i >= n) return;
  if (*flag) out[i] = ((const bf16*)in)[i];
  else       out[i] = (bf16)((const float*)in)[i];
}

// ---------------------------------------------------------------------------
// C[M,N] = A[M,K] @ W[N,K]^T, bf16 in, fp32 accum. 64x64 tile, BK=64.
// ---------------------------------------------------------------------------
__global__ __launch_bounds__(256) void gemm_bt_kernel(
    const bf16* __restrict__ A, const bf16* __restrict__ W,
    void* __restrict__ C, int M, int N, int K,
    const int* __restrict__ outflag) {
  __shared__ bf16 As[64][72];
  __shared__ bf16 Bs[64][72];

  const int n0 = blockIdx.x * 64;
  const int m0 = blockIdx.y * 64;
  const int tid = threadIdx.x;
  const int wave = tid >> 6;
  const int lane = tid & 63;
  const int q16 = lane & 15;
  const int quad = lane >> 4;
  const int f32o = outflag ? (*outflag == 0) : 0;

  f32x4 acc[4];
#pragma unroll
  for (int nt = 0; nt < 4; ++nt) acc[nt] = (f32x4){0.f, 0.f, 0.f, 0.f};

  for (int ko = 0; ko < K; ko += 64) {
#pragma unroll
    for (int rep = 0; rep < 2; ++rep) {
      int c = tid + 256 * rep;
      int r = c >> 3;
      int col8 = (c & 7) * 8;
      *(bf16x8*)&As[r][col8] = *(const bf16x8*)&A[(size_t)(m0 + r) * K + ko + col8];
      *(bf16x8*)&Bs[r][col8] = *(const bf16x8*)&W[(size_t)(n0 + r) * K + ko + col8];
    }
    __syncthreads();

    const int mrow = wave * 16 + q16;
    bf16x8 a0 = *(const bf16x8*)&As[mrow][quad * 8];
    bf16x8 a1 = *(const bf16x8*)&As[mrow][32 + quad * 8];
#pragma unroll
    for (int nt = 0; nt < 4; ++nt) {
      bf16x8 b0 = *(const bf16x8*)&Bs[nt * 16 + q16][quad * 8];
      bf16x8 b1 = *(const bf16x8*)&Bs[nt * 16 + q16][32 + quad * 8];
      acc[nt] = MFMA(a0, b0, acc[nt]);
      acc[nt] = MFMA(a1, b1, acc[nt]);
    }
    __syncthreads();
  }

#pragma unroll
  for (int nt = 0; nt < 4; ++nt)
#pragma unroll
    for (int r = 0; r < 4; ++r) {
      size_t idx = (size_t)(m0 + wave * 16 + quad * 4 + r) * N + n0 + nt * 16 + q16;
      if (f32o) ((float*)C)[idx] = acc[nt][r];
      else      ((bf16*)C)[idx] = (bf16)acc[nt][r];
    }
}

// ---------------------------------------------------------------------------
// RMSNorm + RoPE, in place. One wave per 64-dim row.
// ---------------------------------------------------------------------------
__global__ __launch_bounds__(256) void normrope_kernel(
    bf16* __restrict__ p, const bf16* __restrict__ cosT,
    const bf16* __restrict__ sinT, const bf16* __restrict__ w,
    int heads, float outscale) {
  const int row = blockIdx.x * 4 + (threadIdx.x >> 6);
  const int lane = threadIdx.x & 63;
  const int t = (row / heads) & 2047;
  bf16* rp = p + (size_t)row * 64;

  float v = (float)rp[lane];
  float ss = v * v;
#pragma unroll
  for (int off = 32; off >= 1; off >>= 1) ss += __shfl_xor(ss, off);
  float r = rsqrtf(ss * (1.0f / 64.0f) + 1e-6f);
  float nv = v * r * (float)w[lane];

  float partner = __shfl_xor(nv, 32);
  int j = lane & 31;
  float c = (float)cosT[t * 32 + j];
  float s = (float)sinT[t * 32 + j];
  float out = (lane < 32) ? (nv * c - partner * s) : (nv * c + partner * s);
  rp[lane] = (bf16)(out * outscale);
}

// ---------------------------------------------------------------------------
// V transpose: (B,T,KV,64) -> (B,KV,64,T).
// ---------------------------------------------------------------------------
__global__ __launch_bounds__(256) void vtrans_kernel(
    const bf16* __restrict__ vp, bf16* __restrict__ vt) {
  __shared__ bf16 tile[64][72];
  const int bz = blockIdx.x;
  const int t0 = (bz & 31) * 64;
  const int kv = (bz >> 5) & 3;
  const int b = bz >> 7;
  const int tid = threadIdx.x;

#pragma unroll
  for (int rep = 0; rep < 2; ++rep) {
    int c = tid + 256 * rep;
    int tl = c >> 3;
    int d8 = (c & 7) * 8;
    *(bf16x8*)&tile[tl][d8] =
        *(const bf16x8*)&vp[(((size_t)(b * 2048 + t0 + tl)) * 4 + kv) * 64 + d8];
  }
  __syncthreads();
#pragma unroll
  for (int rep = 0; rep < 2; ++rep) {
    int c = tid + 256 * rep;
    int d = c >> 3;
    int t8 = (c & 7) * 8;
    bf16x8 pk;
#pragma unroll
    for (int j = 0; j < 8; ++j) pk[j] = tile[t8 + j][d];
    *(bf16x8*)&vt[(((size_t)(b * 4 + kv)) * 64 + d) * 2048 + t0 + t8] = pk;
  }
}

// ---------------------------------------------------------------------------
// Flash attention v4: 256-thread block = 4 waves; block covers 64 queries.
// Fixed-max softmax: q pre-scaled 1/8 => ||q'||2<=1, ||k||2<=8 => |S|<=8.
// p = exp(S-9); no online max/rescale. l accumulated via ones-MFMA.
// K,V double-buffered in LDS via register staging; ONE barrier per tile.
// All LDS layouts flat + XOR chunk swizzle (pos = chunk ^ (row&7)).
// qp: (B,T,H,64), kp: (B,T,KV,64), vt: (B,KV,64,T), attn: (B,T,H,64).
// ---------------------------------------------------------------------------
__global__ __launch_bounds__(256, 4) void flash_kernel(
    const bf16* __restrict__ qp, const bf16* __restrict__ kp,
    const bf16* __restrict__ vt, bf16* __restrict__ attn) {
  const int qblk = (int)gridDim.x - 1 - (int)blockIdx.x;  // heavy blocks first
  const int h = blockIdx.y;
  const int b = blockIdx.z;
  const int kvh = h >> 2;
  const int tid = threadIdx.x;
  const int wave = tid >> 6;
  const int lane = tid & 63;
  const int q16 = lane & 15;
  const int quad = lane >> 4;
  const int r7 = q16 & 7;
  const int t0 = qblk * 64 + wave * 16;

  __shared__ bf16 Ks[2][64 * 64];   // 16 KB, swizzled
  __shared__ bf16 Vs[2][64 * 64];   // 16 KB, swizzled
  __shared__ bf16 Pl[4][16 * 64];   //  8 KB, per-wave, swizzled

  const bf16* qrow = qp + (((size_t)(b * 2048 + t0 + q16)) * 16 + h) * 64;
  bf16x8 qa0 = *(const bf16x8*)(qrow + quad * 8);
  bf16x8 qa1 = *(const bf16x8*)(qrow + 32 + quad * 8);

  bf16x8 ones;
#pragma unroll
  for (int j = 0; j < 8; ++j) ones[j] = (bf16)1.0f;

  f32x4 O[4], l4;
#pragma unroll
  for (int nt = 0; nt < 4; ++nt) O[nt] = (f32x4){0.f, 0.f, 0.f, 0.f};
  l4 = (f32x4){0.f, 0.f, 0.f, 0.f};

  const int ntile = qblk + 1;

  // per-thread staging registers (K: 2 chunks, V: 2 chunks)
  bf16x8 kr[2], vr[2];
  const int cr = tid * 2;             // this thread's first chunk id (0..510)
  const int krow = cr >> 3;           // key (for K) / dim (for V), 0..63
  const size_t kgbase = (((size_t)(b * 2048) + krow) * 4 + kvh) * 64;
  const size_t vgbase = ((size_t)(b * 4 + kvh) * 64 + krow) * 2048;

  auto gload = [&](int tk) {
#pragma unroll
    for (int rep = 0; rep < 2; ++rep) {
      int ch = (cr + rep) & 7;
      kr[rep] = *(const bf16x8*)&kp[kgbase + (size_t)(tk * 64) * 256 + ch * 8];
      vr[rep] = *(const bf16x8*)&vt[vgbase + tk * 64 + ch * 8];
    }
  };
  auto swrite = [&](int bb) {
#pragma unroll
    for (int rep = 0; rep < 2; ++rep) {
      int ch = (cr + rep) & 7;
      int pos = (ch ^ (krow & 7)) * 8;
      *(bf16x8*)&Ks[bb][krow * 64 + pos] = kr[rep];
      *(bf16x8*)&Vs[bb][krow * 64 + pos] = vr[rep];
    }
  };

  gload(0);

  for (int t = 0; t < ntile; ++t) {
    const int bb = t & 1;
    const int kbase = t * 64;
    swrite(bb);        // vmcnt wait (prev gload) lands here, covered by compute
    __syncthreads();   // single barrier per tile (dbuf makes 2nd unnecessary)
    if (t + 1 < ntile) gload(t + 1);

    // S = Q K^T : 4 key subtiles of 16
    f32x4 s[4];
#pragma unroll
    for (int kt = 0; kt < 4; ++kt) {
      const bf16* kr0 = &Ks[bb][(kt * 16 + q16) * 64];
      bf16x8 kb0 = *(const bf16x8*)&kr0[(quad ^ r7) * 8];
      bf16x8 kb1 = *(const bf16x8*)&kr0[((quad + 4) ^ r7) * 8];
      f32x4 z = (f32x4){0.f, 0.f, 0.f, 0.f};
      z = MFMA(qa0, kb0, z);
      z = MFMA(qa1, kb1, z);
      s[kt] = z;
    }

    // causal mask — only the last tile straddles the diagonal
    if (kbase + 63 > t0) {
#pragma unroll
      for (int kt = 0; kt < 4; ++kt) {
        int jt = kbase + kt * 16 + q16;
#pragma unroll
        for (int r = 0; r < 4; ++r)
          if (jt > t0 + quad * 4 + r) s[kt][r] = -1e30f;
      }
    }

    // p = exp(S - 9): |S| <= 8 provably (RMSNorm bound), so no online max.
#pragma unroll
    for (int kt = 0; kt < 4; ++kt)
#pragma unroll
      for (int r = 0; r < 4; ++r) s[kt][r] = __expf(s[kt][r] - 9.0f);

    // P: C/D layout -> per-wave LDS (swizzled) -> A layout
#pragma unroll
    for (int kt = 0; kt < 4; ++kt)
#pragma unroll
      for (int r = 0; r < 4; ++r) {
        int row = quad * 4 + r;
        int col = kt * 16 + q16;
        Pl[wave][row * 64 + ((col >> 3) ^ (row & 7)) * 8 + (col & 7)] =
            (bf16)s[kt][r];
      }

    // O += P V ; l += P 1  (two 32-key halves)
#pragma unroll
    for (int kh = 0; kh < 2; ++kh) {
      bf16x8 pa = *(const bf16x8*)&Pl[wave][q16 * 64 +
                                           (((kh * 4 + quad) ^ r7) * 8)];
#pragma unroll
      for (int nt = 0; nt < 4; ++nt) {
        const bf16* vr0 = &Vs[bb][(nt * 16 + q16) * 64];
        bf16x8 vb = *(const bf16x8*)&vr0[((kh * 4 + quad) ^ r7) * 8];
        O[nt] = MFMA(pa, vb, O[nt]);
      }
      l4 = MFMA(pa, ones, l4);
    }
  }

  float inv[4];
#pragma unroll
  for (int r = 0; r < 4; ++r) inv[r] = 1.0f / l4[r];
#pragma unroll
  for (int nt = 0; nt < 4; ++nt)
#pragma unroll
    for (int r = 0; r < 4; ++r) {
      size_t o = (((size_t)(b * 2048 + t0 + quad * 4 + r)) * 16 + h) * 64 +
                 nt * 16 + q16;
      attn[o] = (bf16)(O[nt][r] * inv[r]);
    }
}

// ---------------------------------------------------------------------------
extern "C" void kernel_launch(void* const* d_in, const int* in_sizes, int n_in,
                              void* d_out, int out_size, void* d_ws, size_t ws_size,
                              hipStream_t stream) {
  bf16* xc  = (bf16*)d_ws;                   // aliased as `at` after last use
  bf16* qp  = xc  + (size_t)4096 * 1024;
  bf16* kp  = qp  + (size_t)4096 * 1024;
  bf16* vp  = kp  + (size_t)4096 * 256;
  bf16* vt  = vp  + (size_t)4096 * 256;
  bf16* wqc = vt  + (size_t)4096 * 256;
  bf16* wkc = wqc + (size_t)1024 * 1024;
  bf16* wvc = wkc + (size_t)256 * 1024;
  bf16* woc = wvc + (size_t)256 * 1024;
  bf16* csc = woc + (size_t)1024 * 1024;
  bf16* snc = csc + (size_t)2048 * 32;
  bf16* qnc = snc + (size_t)2048 * 32;
  bf16* knc = qnc + 64;
  int* flag = (int*)(knc + 64);
  bf16* at  = xc;

  detect_kernel<<<1, 1, 0, stream>>>((const unsigned short*)d_in[1], flag);

  struct { const void* src; bf16* dst; int n; } cv[9] = {
      {d_in[0], xc,  4096 * 1024}, {d_in[1], csc, 2048 * 32},
      {d_in[2], snc, 2048 * 32},   {d_in[3], wqc, 1024 * 1024},
      {d_in[4], wkc, 256 * 1024},  {d_in[5], wvc, 256 * 1024},
      {d_in[6], woc, 1024 * 1024}, {d_in[7], qnc, 64},
      {d_in[8], knc, 64}};
  for (int i = 0; i < 9; ++i)
    convert_kernel<<<(cv[i].n + 255) / 256, 256, 0, stream>>>(cv[i].src, cv[i].dst,
                                                              cv[i].n, flag);

  gemm_bt_kernel<<<dim3(16, 64), 256, 0, stream>>>(xc, wqc, qp, 4096, 1024, 1024, nullptr);
  gemm_bt_kernel<<<dim3(4, 64), 256, 0, stream>>>(xc, wkc, kp, 4096, 256, 1024, nullptr);
  gemm_bt_kernel<<<dim3(4, 64), 256, 0, stream>>>(xc, wvc, vp, 4096, 256, 1024, nullptr);

  normrope_kernel<<<16384, 256, 0, stream>>>(qp, csc, snc, qnc, 16, 0.125f);
  normrope_kernel<<<4096, 256, 0, stream>>>(kp, csc, snc, knc, 4, 1.0f);

  vtrans_kernel<<<256, 256, 0, stream>>>(vp, vt);

  flash_kernel<<<dim3(32, 16, 2), 256, 0, stream>>>(qp, kp, vt, at);

  gemm_bt_kernel<<<dim3(16, 64), 256, 0, stream>>>(at, woc, d_out, 4096, 1024, 1024, flag);
}

// Round 6
// 252.107 us; speedup vs baseline: 1.8127x; 1.1339x over previous
//
#include <hip/hip_runtime.h>

// GQA prefill block, MI355X gfx950. Inputs bf16 (auto-detected vs fp32 via
// cos[0][0] bit pattern; canonicalized to bf16).
// Round 5: (1) flash load-balance swizzle (qblk mixed per CU);
// (2) q/o projections on m97-style 128x128 GEMM w/ global_load_lds + XOR
// swizzle; (3) all input converts fused into one kernel.

typedef __bf16 bf16;
typedef __attribute__((ext_vector_type(8))) __bf16 bf16x8;
typedef __attribute__((ext_vector_type(4))) float f32x4;

#define MFMA(a, b, c) __builtin_amdgcn_mfma_f32_16x16x32_bf16((a), (b), (c), 0, 0, 0)
#define GLOAD_LDS16(g, l)                                        \
  __builtin_amdgcn_global_load_lds(                              \
      (const __attribute__((address_space(1))) void*)(g),        \
      (__attribute__((address_space(3))) void*)(l), 16, 0, 0)

// ---------------------------------------------------------------------------
__global__ void detect_kernel(const unsigned short* __restrict__ cosRaw,
                              int* __restrict__ flag) {
  *flag = (cosRaw[0] == 0x3F80) ? 1 : 0;  // 1=bf16 input, 0=fp32 input
}

// all-inputs convert, one launch. Segments ordered big-first.
struct CvArgs {
  const void* src[9];
  bf16* dst[9];
  int end[9];  // cumulative ends
};

__global__ __launch_bounds__(256) void convert_all_kernel(
    CvArgs a, const int* __restrict__ flag) {
  int i = blockIdx.x * 256 + threadIdx.x;
  if (i >= a.end[8]) return;
  int s = 0;
#pragma unroll
  for (int k = 0; k < 8; ++k) s += (i >= a.end[k]) ? 1 : 0;
  int local = i - (s ? a.end[s - 1] : 0);
  if (*flag) a.dst[s][local] = ((const bf16*)a.src[s])[local];
  else       a.dst[s][local] = (bf16)((const float*)a.src[s])[local];
}

// ---------------------------------------------------------------------------
// 64x64-tile GEMM (kept for the small k/v projections). C=A@W^T.
// ---------------------------------------------------------------------------
__global__ __launch_bounds__(256) void gemm_bt_kernel(
    const bf16* __restrict__ A, const bf16* __restrict__ W,
    void* __restrict__ C, int M, int N, int K,
    const int* __restrict__ outflag) {
  __shared__ bf16 As[64][72];
  __shared__ bf16 Bs[64][72];

  const int n0 = blockIdx.x * 64;
  const int m0 = blockIdx.y * 64;
  const int tid = threadIdx.x;
  const int wave = tid >> 6;
  const int lane = tid & 63;
  const int q16 = lane & 15;
  const int quad = lane >> 4;
  const int f32o = outflag ? (*outflag == 0) : 0;

  f32x4 acc[4];
#pragma unroll
  for (int nt = 0; nt < 4; ++nt) acc[nt] = (f32x4){0.f, 0.f, 0.f, 0.f};

  for (int ko = 0; ko < K; ko += 64) {
#pragma unroll
    for (int rep = 0; rep < 2; ++rep) {
      int c = tid + 256 * rep;
      int r = c >> 3;
      int col8 = (c & 7) * 8;
      *(bf16x8*)&As[r][col8] = *(const bf16x8*)&A[(size_t)(m0 + r) * K + ko + col8];
      *(bf16x8*)&Bs[r][col8] = *(const bf16x8*)&W[(size_t)(n0 + r) * K + ko + col8];
    }
    __syncthreads();

    const int mrow = wave * 16 + q16;
    bf16x8 a0 = *(const bf16x8*)&As[mrow][quad * 8];
    bf16x8 a1 = *(const bf16x8*)&As[mrow][32 + quad * 8];
#pragma unroll
    for (int nt = 0; nt < 4; ++nt) {
      bf16x8 b0 = *(const bf16x8*)&Bs[nt * 16 + q16][quad * 8];
      bf16x8 b1 = *(const bf16x8*)&Bs[nt * 16 + q16][32 + quad * 8];
      acc[nt] = MFMA(a0, b0, acc[nt]);
      acc[nt] = MFMA(a1, b1, acc[nt]);
    }
    __syncthreads();
  }

#pragma unroll
  for (int nt = 0; nt < 4; ++nt)
#pragma unroll
    for (int r = 0; r < 4; ++r) {
      size_t idx = (size_t)(m0 + wave * 16 + quad * 4 + r) * N + n0 + nt * 16 + q16;
      if (f32o) ((float*)C)[idx] = acc[nt][r];
      else      ((bf16*)C)[idx] = (bf16)acc[nt][r];
    }
}

// ---------------------------------------------------------------------------
// m97-style 128x128-tile GEMM, BK=64, global_load_lds(16B) staging with
// source-side XOR chunk swizzle (conflict-free ds_read_b128 fragments).
// 4 waves in 2x2; each wave computes 64x64 (4x4 MFMA frags).
// ---------------------------------------------------------------------------
__global__ __launch_bounds__(256) void gemm128_kernel(
    const bf16* __restrict__ A, const bf16* __restrict__ W,
    void* __restrict__ C, int M, int N, int K,
    const int* __restrict__ outflag) {
  __shared__ bf16 As[128 * 64];  // row-major, chunk pos p holds src chunk p^(r&7)
  __shared__ bf16 Bs[128 * 64];

  const int n0 = blockIdx.x * 128;
  const int m0 = blockIdx.y * 128;
  const int tid = threadIdx.x;
  const int wave = tid >> 6;
  const int lane = tid & 63;
  const int q16 = lane & 15;
  const int quad = lane >> 4;
  const int f32o = outflag ? (*outflag == 0) : 0;

  const int srow = lane >> 3;                 // 0..7 within 8-row group
  const int csrc = (lane & 7) ^ srow;         // swizzled source chunk
  const int wm = (wave >> 1) * 64;
  const int wn = (wave & 1) * 64;
  const int x7 = q16 & 7;

  f32x4 acc[4][4];
#pragma unroll
  for (int mt = 0; mt < 4; ++mt)
#pragma unroll
    for (int nt = 0; nt < 4; ++nt) acc[mt][nt] = (f32x4){0.f, 0.f, 0.f, 0.f};

  for (int ko = 0; ko < K; ko += 64) {
    __syncthreads();  // prev-tile LDS reads complete before overwrite
#pragma unroll
    for (int i = 0; i < 4; ++i) {
      int rb = wave * 32 + i * 8;
      GLOAD_LDS16(&A[(size_t)(m0 + rb + srow) * K + ko + csrc * 8],
                  &As[rb * 64]);
      GLOAD_LDS16(&W[(size_t)(n0 + rb + srow) * K + ko + csrc * 8],
                  &Bs[rb * 64]);
    }
    __syncthreads();  // DMA drained (vmcnt 0 before barrier)

    bf16x8 af[4][2], bfr[4][2];
#pragma unroll
    for (int mt = 0; mt < 4; ++mt) {
      const bf16* rp = &As[(wm + mt * 16 + q16) * 64];
      af[mt][0] = *(const bf16x8*)&rp[(quad ^ x7) * 8];
      af[mt][1] = *(const bf16x8*)&rp[((quad + 4) ^ x7) * 8];
    }
#pragma unroll
    for (int nt = 0; nt < 4; ++nt) {
      const bf16* rp = &Bs[(wn + nt * 16 + q16) * 64];
      bfr[nt][0] = *(const bf16x8*)&rp[(quad ^ x7) * 8];
      bfr[nt][1] = *(const bf16x8*)&rp[((quad + 4) ^ x7) * 8];
    }
#pragma unroll
    for (int mt = 0; mt < 4; ++mt)
#pragma unroll
      for (int nt = 0; nt < 4; ++nt) {
        acc[mt][nt] = MFMA(af[mt][0], bfr[nt][0], acc[mt][nt]);
        acc[mt][nt] = MFMA(af[mt][1], bfr[nt][1], acc[mt][nt]);
      }
  }

#pragma unroll
  for (int mt = 0; mt < 4; ++mt)
#pragma unroll
    for (int nt = 0; nt < 4; ++nt)
#pragma unroll
      for (int r = 0; r < 4; ++r) {
        size_t idx = (size_t)(m0 + wm + mt * 16 + quad * 4 + r) * N +
                     n0 + wn + nt * 16 + q16;
        if (f32o) ((float*)C)[idx] = acc[mt][nt][r];
        else      ((bf16*)C)[idx] = (bf16)acc[mt][nt][r];
      }
}

// ---------------------------------------------------------------------------
// RMSNorm + RoPE, in place. One wave per 64-dim row.
// ---------------------------------------------------------------------------
__global__ __launch_bounds__(256) void normrope_kernel(
    bf16* __restrict__ p, const bf16* __restrict__ cosT,
    const bf16* __restrict__ sinT, const bf16* __restrict__ w,
    int heads, float outscale) {
  const int row = blockIdx.x * 4 + (threadIdx.x >> 6);
  const int lane = threadIdx.x & 63;
  const int t = (row / heads) & 2047;
  bf16* rp = p + (size_t)row * 64;

  float v = (float)rp[lane];
  float ss = v * v;
#pragma unroll
  for (int off = 32; off >= 1; off >>= 1) ss += __shfl_xor(ss, off);
  float r = rsqrtf(ss * (1.0f / 64.0f) + 1e-6f);
  float nv = v * r * (float)w[lane];

  float partner = __shfl_xor(nv, 32);
  int j = lane & 31;
  float c = (float)cosT[t * 32 + j];
  float s = (float)sinT[t * 32 + j];
  float out = (lane < 32) ? (nv * c - partner * s) : (nv * c + partner * s);
  rp[lane] = (bf16)(out * outscale);
}

// ---------------------------------------------------------------------------
// V transpose: (B,T,KV,64) -> (B,KV,64,T).
// ---------------------------------------------------------------------------
__global__ __launch_bounds__(256) void vtrans_kernel(
    const bf16* __restrict__ vp, bf16* __restrict__ vt) {
  __shared__ bf16 tile[64][72];
  const int bz = blockIdx.x;
  const int t0 = (bz & 31) * 64;
  const int kv = (bz >> 5) & 3;
  const int b = bz >> 7;
  const int tid = threadIdx.x;

#pragma unroll
  for (int rep = 0; rep < 2; ++rep) {
    int c = tid + 256 * rep;
    int tl = c >> 3;
    int d8 = (c & 7) * 8;
    *(bf16x8*)&tile[tl][d8] =
        *(const bf16x8*)&vp[(((size_t)(b * 2048 + t0 + tl)) * 4 + kv) * 64 + d8];
  }
  __syncthreads();
#pragma unroll
  for (int rep = 0; rep < 2; ++rep) {
    int c = tid + 256 * rep;
    int d = c >> 3;
    int t8 = (c & 7) * 8;
    bf16x8 pk;
#pragma unroll
    for (int j = 0; j < 8; ++j) pk[j] = tile[t8 + j][d];
    *(bf16x8*)&vt[(((size_t)(b * 4 + kv)) * 64 + d) * 2048 + t0 + t8] = pk;
  }
}

// ---------------------------------------------------------------------------
// Flash attention v5: v4 + load-balance swizzle. 256 threads = 4 waves,
// block covers 64 queries. Fixed-max softmax exp(S-9) (|S|<=8 after RMSNorm
// with q pre-scaled 1/8). l via ones-MFMA. K,V LDS dbuf via register staging,
// one barrier/tile. XOR-swizzled LDS (0 bank conflicts measured).
// qblk = (31-x + y + 16z) & 31: each CU's 4 blocks get {a,a+8,a+16,a+24}.
// ---------------------------------------------------------------------------
__global__ __launch_bounds__(256, 4) void flash_kernel(
    const bf16* __restrict__ qp, const bf16* __restrict__ kp,
    const bf16* __restrict__ vt, bf16* __restrict__ attn) {
  const int qblk = (31 - (int)blockIdx.x + (int)blockIdx.y + 16 * (int)blockIdx.z) & 31;
  const int h = blockIdx.y;
  const int b = blockIdx.z;
  const int kvh = h >> 2;
  const int tid = threadIdx.x;
  const int wave = tid >> 6;
  const int lane = tid & 63;
  const int q16 = lane & 15;
  const int quad = lane >> 4;
  const int r7 = q16 & 7;
  const int t0 = qblk * 64 + wave * 16;

  __shared__ bf16 Ks[2][64 * 64];
  __shared__ bf16 Vs[2][64 * 64];
  __shared__ bf16 Pl[4][16 * 64];

  const bf16* qrow = qp + (((size_t)(b * 2048 + t0 + q16)) * 16 + h) * 64;
  bf16x8 qa0 = *(const bf16x8*)(qrow + quad * 8);
  bf16x8 qa1 = *(const bf16x8*)(qrow + 32 + quad * 8);

  bf16x8 ones;
#pragma unroll
  for (int j = 0; j < 8; ++j) ones[j] = (bf16)1.0f;

  f32x4 O[4], l4;
#pragma unroll
  for (int nt = 0; nt < 4; ++nt) O[nt] = (f32x4){0.f, 0.f, 0.f, 0.f};
  l4 = (f32x4){0.f, 0.f, 0.f, 0.f};

  const int ntile = qblk + 1;

  bf16x8 kr[2], vr[2];
  const int cr = tid * 2;
  const int krow = cr >> 3;
  const size_t kgbase = (((size_t)(b * 2048) + krow) * 4 + kvh) * 64;
  const size_t vgbase = ((size_t)(b * 4 + kvh) * 64 + krow) * 2048;

  auto gload = [&](int tk) {
#pragma unroll
    for (int rep = 0; rep < 2; ++rep) {
      int ch = (cr + rep) & 7;
      kr[rep] = *(const bf16x8*)&kp[kgbase + (size_t)(tk * 64) * 256 + ch * 8];
      vr[rep] = *(const bf16x8*)&vt[vgbase + tk * 64 + ch * 8];
    }
  };
  auto swrite = [&](int bb) {
#pragma unroll
    for (int rep = 0; rep < 2; ++rep) {
      int ch = (cr + rep) & 7;
      int pos = (ch ^ (krow & 7)) * 8;
      *(bf16x8*)&Ks[bb][krow * 64 + pos] = kr[rep];
      *(bf16x8*)&Vs[bb][krow * 64 + pos] = vr[rep];
    }
  };

  gload(0);

  for (int t = 0; t < ntile; ++t) {
    const int bb = t & 1;
    const int kbase = t * 64;
    swrite(bb);
    __syncthreads();
    if (t + 1 < ntile) gload(t + 1);

    f32x4 s[4];
#pragma unroll
    for (int kt = 0; kt < 4; ++kt) {
      const bf16* kr0 = &Ks[bb][(kt * 16 + q16) * 64];
      bf16x8 kb0 = *(const bf16x8*)&kr0[(quad ^ r7) * 8];
      bf16x8 kb1 = *(const bf16x8*)&kr0[((quad + 4) ^ r7) * 8];
      f32x4 z = (f32x4){0.f, 0.f, 0.f, 0.f};
      z = MFMA(qa0, kb0, z);
      z = MFMA(qa1, kb1, z);
      s[kt] = z;
    }

    if (kbase + 63 > t0) {
#pragma unroll
      for (int kt = 0; kt < 4; ++kt) {
        int jt = kbase + kt * 16 + q16;
#pragma unroll
        for (int r = 0; r < 4; ++r)
          if (jt > t0 + quad * 4 + r) s[kt][r] = -1e30f;
      }
    }

#pragma unroll
    for (int kt = 0; kt < 4; ++kt)
#pragma unroll
      for (int r = 0; r < 4; ++r) s[kt][r] = __expf(s[kt][r] - 9.0f);

#pragma unroll
    for (int kt = 0; kt < 4; ++kt)
#pragma unroll
      for (int r = 0; r < 4; ++r) {
        int row = quad * 4 + r;
        int col = kt * 16 + q16;
        Pl[wave][row * 64 + ((col >> 3) ^ (row & 7)) * 8 + (col & 7)] =
            (bf16)s[kt][r];
      }

#pragma unroll
    for (int kh = 0; kh < 2; ++kh) {
      bf16x8 pa = *(const bf16x8*)&Pl[wave][q16 * 64 +
                                           (((kh * 4 + quad) ^ r7) * 8)];
#pragma unroll
      for (int nt = 0; nt < 4; ++nt) {
        const bf16* vr0 = &Vs[bb][(nt * 16 + q16) * 64];
        bf16x8 vb = *(const bf16x8*)&vr0[((kh * 4 + quad) ^ r7) * 8];
        O[nt] = MFMA(pa, vb, O[nt]);
      }
      l4 = MFMA(pa, ones, l4);
    }
  }

  float inv[4];
#pragma unroll
  for (int r = 0; r < 4; ++r) inv[r] = 1.0f / l4[r];
#pragma unroll
  for (int nt = 0; nt < 4; ++nt)
#pragma unroll
    for (int r = 0; r < 4; ++r) {
      size_t o = (((size_t)(b * 2048 + t0 + quad * 4 + r)) * 16 + h) * 64 +
                 nt * 16 + q16;
      attn[o] = (bf16)(O[nt][r] * inv[r]);
    }
}

// ---------------------------------------------------------------------------
extern "C" void kernel_launch(void* const* d_in, const int* in_sizes, int n_in,
                              void* d_out, int out_size, void* d_ws, size_t ws_size,
                              hipStream_t stream) {
  bf16* xc  = (bf16*)d_ws;                   // aliased as `at` after last use
  bf16* qp  = xc  + (size_t)4096 * 1024;
  bf16* kp  = qp  + (size_t)4096 * 1024;
  bf16* vp  = kp  + (size_t)4096 * 256;
  bf16* vt  = vp  + (size_t)4096 * 256;
  bf16* wqc = vt  + (size_t)4096 * 256;
  bf16* wkc = wqc + (size_t)1024 * 1024;
  bf16* wvc = wkc + (size_t)256 * 1024;
  bf16* woc = wvc + (size_t)256 * 1024;
  bf16* csc = woc + (size_t)1024 * 1024;
  bf16* snc = csc + (size_t)2048 * 32;
  bf16* qnc = snc + (size_t)2048 * 32;
  bf16* knc = qnc + 64;
  int* flag = (int*)(knc + 64);
  bf16* at  = xc;

  detect_kernel<<<1, 1, 0, stream>>>((const unsigned short*)d_in[1], flag);

  // fused converts (big segments first)
  CvArgs cva;
  const void* srcs[9] = {d_in[0], d_in[3], d_in[6], d_in[4], d_in[5],
                         d_in[1], d_in[2], d_in[7], d_in[8]};
  bf16* dsts[9] = {xc, wqc, woc, wkc, wvc, csc, snc, qnc, knc};
  int lens[9] = {4096 * 1024, 1024 * 1024, 1024 * 1024, 256 * 1024, 256 * 1024,
                 2048 * 32, 2048 * 32, 64, 64};
  int acc = 0;
  for (int i = 0; i < 9; ++i) {
    cva.src[i] = srcs[i];
    cva.dst[i] = dsts[i];
    acc += lens[i];
    cva.end[i] = acc;
  }
  convert_all_kernel<<<(acc + 255) / 256, 256, 0, stream>>>(cva, flag);

  // projections: q via 128-tile, k/v via 64-tile
  gemm128_kernel<<<dim3(8, 32), 256, 0, stream>>>(xc, wqc, qp, 4096, 1024, 1024, nullptr);
  gemm_bt_kernel<<<dim3(4, 64), 256, 0, stream>>>(xc, wkc, kp, 4096, 256, 1024, nullptr);
  gemm_bt_kernel<<<dim3(4, 64), 256, 0, stream>>>(xc, wvc, vp, 4096, 256, 1024, nullptr);

  normrope_kernel<<<16384, 256, 0, stream>>>(qp, csc, snc, qnc, 16, 0.125f);
  normrope_kernel<<<4096, 256, 0, stream>>>(kp, csc, snc, knc, 4, 1.0f);

  vtrans_kernel<<<256, 256, 0, stream>>>(vp, vt);

  flash_kernel<<<dim3(32, 16, 2), 256, 0, stream>>>(qp, kp, vt, at);

  // output projection via 128-tile
  gemm128_kernel<<<dim3(8, 32), 256, 0, stream>>>(at, woc, d_out, 4096, 1024, 1024, flag);
}

// Round 7
// 206.887 us; speedup vs baseline: 2.2089x; 1.2186x over previous
//
#include <hip/hip_runtime.h>

// GQA prefill block, MI355X gfx950. Inputs bf16 (auto-detected vs fp32 via
// cos[0][0] bit pattern). Round 6: fused to 5 dispatches —
// convert | qproj+norm+rope | kvproj+norm+rope+vtrans | flash | oproj.

typedef __bf16 bf16;
typedef __attribute__((ext_vector_type(8))) __bf16 bf16x8;
typedef __attribute__((ext_vector_type(4))) float f32x4;

#define MFMA(a, b, c) __builtin_amdgcn_mfma_f32_16x16x32_bf16((a), (b), (c), 0, 0, 0)
#define GLOAD_LDS16(g, l)                                        \
  __builtin_amdgcn_global_load_lds(                              \
      (const __attribute__((address_space(1))) void*)(g),        \
      (__attribute__((address_space(3))) void*)(l), 16, 0, 0)

__device__ __forceinline__ bool is_bf16_input(const unsigned short* cosRaw) {
  return cosRaw[0] == 0x3F80;  // cos(0)=1.0 as bf16; fp32 LE low half = 0
}

// ---------------------------------------------------------------------------
// all-inputs convert, one launch, 8 elems/thread.
// ---------------------------------------------------------------------------
struct CvArgs {
  const void* src[9];
  bf16* dst[9];
  int end[9];  // cumulative elem ends (all multiples of 8)
};

__global__ __launch_bounds__(256) void convert_all_kernel(
    CvArgs a, const unsigned short* __restrict__ cosRaw) {
  int i = (blockIdx.x * 256 + threadIdx.x) * 8;
  if (i >= a.end[8]) return;
  int s = 0;
#pragma unroll
  for (int k = 0; k < 8; ++k) s += (i >= a.end[k]) ? 1 : 0;
  int local = i - (s ? a.end[s - 1] : 0);
  if (is_bf16_input(cosRaw)) {
    *(bf16x8*)&a.dst[s][local] = *(const bf16x8*)&((const bf16*)a.src[s])[local];
  } else {
    const float* fp = &((const float*)a.src[s])[local];
    bf16x8 o;
#pragma unroll
    for (int j = 0; j < 8; ++j) o[j] = (bf16)fp[j];
    *(bf16x8*)&a.dst[s][local] = o;
  }
}

// ---------------------------------------------------------------------------
// q-projection: C=A@Wq^T on 128x128 tiles (global_load_lds + XOR swizzle),
// fused epilogue: RMSNorm(64) + RoPE + 1/8 scale -> qp (B,T,H,64) bf16.
// Wave n-range (64 cols) == one head; norm = 16-lane shfl reduce;
// RoPE partner d+32 is register pair nt<->nt+2.
// ---------------------------------------------------------------------------
__global__ __launch_bounds__(256) void gemm_q_kernel(
    const bf16* __restrict__ A, const bf16* __restrict__ W,
    bf16* __restrict__ qp, const bf16* __restrict__ cosT,
    const bf16* __restrict__ sinT, const bf16* __restrict__ nw, int K) {
  __shared__ bf16 As[128 * 64];
  __shared__ bf16 Bs[128 * 64];

  const int n0 = blockIdx.x * 128;
  const int m0 = blockIdx.y * 128;
  const int tid = threadIdx.x;
  const int wave = tid >> 6;
  const int lane = tid & 63;
  const int q16 = lane & 15;
  const int quad = lane >> 4;
  const int srow = lane >> 3;
  const int csrc = (lane & 7) ^ srow;
  const int wm = (wave >> 1) * 64;
  const int wn = (wave & 1) * 64;
  const int x7 = q16 & 7;

  f32x4 acc[4][4];
#pragma unroll
  for (int mt = 0; mt < 4; ++mt)
#pragma unroll
    for (int nt = 0; nt < 4; ++nt) acc[mt][nt] = (f32x4){0.f, 0.f, 0.f, 0.f};

  for (int ko = 0; ko < K; ko += 64) {
    __syncthreads();
#pragma unroll
    for (int i = 0; i < 4; ++i) {
      int rb = wave * 32 + i * 8;
      GLOAD_LDS16(&A[(size_t)(m0 + rb + srow) * K + ko + csrc * 8], &As[rb * 64]);
      GLOAD_LDS16(&W[(size_t)(n0 + rb + srow) * K + ko + csrc * 8], &Bs[rb * 64]);
    }
    __syncthreads();

    bf16x8 af[4][2], bfr[4][2];
#pragma unroll
    for (int mt = 0; mt < 4; ++mt) {
      const bf16* rp = &As[(wm + mt * 16 + q16) * 64];
      af[mt][0] = *(const bf16x8*)&rp[(quad ^ x7) * 8];
      af[mt][1] = *(const bf16x8*)&rp[((quad + 4) ^ x7) * 8];
    }
#pragma unroll
    for (int nt = 0; nt < 4; ++nt) {
      const bf16* rp = &Bs[(wn + nt * 16 + q16) * 64];
      bfr[nt][0] = *(const bf16x8*)&rp[(quad ^ x7) * 8];
      bfr[nt][1] = *(const bf16x8*)&rp[((quad + 4) ^ x7) * 8];
    }
#pragma unroll
    for (int mt = 0; mt < 4; ++mt)
#pragma unroll
      for (int nt = 0; nt < 4; ++nt) {
        acc[mt][nt] = MFMA(af[mt][0], bfr[nt][0], acc[mt][nt]);
        acc[mt][nt] = MFMA(af[mt][1], bfr[nt][1], acc[mt][nt]);
      }
  }

  // fused RMSNorm + RoPE + 1/8 scale epilogue
  float wd[4];
#pragma unroll
  for (int nt = 0; nt < 4; ++nt) wd[nt] = (float)nw[nt * 16 + q16];

#pragma unroll
  for (int mt = 0; mt < 4; ++mt)
#pragma unroll
    for (int r = 0; r < 4; ++r) {
      float p = acc[mt][0][r] * acc[mt][0][r] + acc[mt][1][r] * acc[mt][1][r] +
                acc[mt][2][r] * acc[mt][2][r] + acc[mt][3][r] * acc[mt][3][r];
#pragma unroll
      for (int off = 8; off >= 1; off >>= 1) p += __shfl_xor(p, off);
      float rms = rsqrtf(p * (1.0f / 64.0f) + 1e-6f);

      int row = m0 + wm + mt * 16 + quad * 4 + r;
      int t = row & 2047;
      float c0 = (float)cosT[t * 32 + q16];
      float c1 = (float)cosT[t * 32 + 16 + q16];
      float s0 = (float)sinT[t * 32 + q16];
      float s1 = (float)sinT[t * 32 + 16 + q16];

      float v0 = acc[mt][0][r] * rms * wd[0];
      float v1 = acc[mt][1][r] * rms * wd[1];
      float v2 = acc[mt][2][r] * rms * wd[2];
      float v3 = acc[mt][3][r] * rms * wd[3];

      bf16* op = &qp[(size_t)row * 1024 + n0 + wn];
      op[0 * 16 + q16] = (bf16)((v0 * c0 - v2 * s0) * 0.125f);
      op[1 * 16 + q16] = (bf16)((v1 * c1 - v3 * s1) * 0.125f);
      op[2 * 16 + q16] = (bf16)((v2 * c0 + v0 * s0) * 0.125f);
      op[3 * 16 + q16] = (bf16)((v3 * c1 + v1 * s1) * 0.125f);
    }
}

// ---------------------------------------------------------------------------
// k+v projection in one launch: C=A@Wkv^T (Wkv = [512][1024], wk rows then
// wv rows). 64x64 tiles, grid (8,64). Blocks n0<256: k-head -> RMSNorm+RoPE
// -> kp (B,T,KV,64). Blocks n0>=256: v-head -> LDS transpose -> vt
// (B,KV,64,T).
// ---------------------------------------------------------------------------
__global__ __launch_bounds__(256) void gemm_kv_kernel(
    const bf16* __restrict__ A, const bf16* __restrict__ Wkv,
    bf16* __restrict__ kp, bf16* __restrict__ vt,
    const bf16* __restrict__ cosT, const bf16* __restrict__ sinT,
    const bf16* __restrict__ nw, int K) {
  __shared__ bf16 As[64][72];
  __shared__ bf16 Bs[64][72];

  const int n0 = blockIdx.x * 64;
  const int m0 = blockIdx.y * 64;
  const int tid = threadIdx.x;
  const int wave = tid >> 6;
  const int lane = tid & 63;
  const int q16 = lane & 15;
  const int quad = lane >> 4;

  f32x4 acc[4];
#pragma unroll
  for (int nt = 0; nt < 4; ++nt) acc[nt] = (f32x4){0.f, 0.f, 0.f, 0.f};

  for (int ko = 0; ko < K; ko += 64) {
#pragma unroll
    for (int rep = 0; rep < 2; ++rep) {
      int c = tid + 256 * rep;
      int r = c >> 3;
      int col8 = (c & 7) * 8;
      *(bf16x8*)&As[r][col8] = *(const bf16x8*)&A[(size_t)(m0 + r) * K + ko + col8];
      *(bf16x8*)&Bs[r][col8] = *(const bf16x8*)&Wkv[(size_t)(n0 + r) * K + ko + col8];
    }
    __syncthreads();

    const int mrow = wave * 16 + q16;
    bf16x8 a0 = *(const bf16x8*)&As[mrow][quad * 8];
    bf16x8 a1 = *(const bf16x8*)&As[mrow][32 + quad * 8];
#pragma unroll
    for (int nt = 0; nt < 4; ++nt) {
      bf16x8 b0 = *(const bf16x8*)&Bs[nt * 16 + q16][quad * 8];
      bf16x8 b1 = *(const bf16x8*)&Bs[nt * 16 + q16][32 + quad * 8];
      acc[nt] = MFMA(a0, b0, acc[nt]);
      acc[nt] = MFMA(a1, b1, acc[nt]);
    }
    __syncthreads();
  }

  if (n0 < 256) {
    // K path: RMSNorm + RoPE -> kp[row*256 + n0 + d]
    float wd[4];
#pragma unroll
    for (int nt = 0; nt < 4; ++nt) wd[nt] = (float)nw[nt * 16 + q16];
#pragma unroll
    for (int r = 0; r < 4; ++r) {
      float p = acc[0][r] * acc[0][r] + acc[1][r] * acc[1][r] +
                acc[2][r] * acc[2][r] + acc[3][r] * acc[3][r];
#pragma unroll
      for (int off = 8; off >= 1; off >>= 1) p += __shfl_xor(p, off);
      float rms = rsqrtf(p * (1.0f / 64.0f) + 1e-6f);

      int row = m0 + wave * 16 + quad * 4 + r;
      int t = row & 2047;
      float c0 = (float)cosT[t * 32 + q16];
      float c1 = (float)cosT[t * 32 + 16 + q16];
      float s0 = (float)sinT[t * 32 + q16];
      float s1 = (float)sinT[t * 32 + 16 + q16];

      float v0 = acc[0][r] * rms * wd[0];
      float v1 = acc[1][r] * rms * wd[1];
      float v2 = acc[2][r] * rms * wd[2];
      float v3 = acc[3][r] * rms * wd[3];

      bf16* op = &kp[(size_t)row * 256 + n0];
      op[0 * 16 + q16] = (bf16)(v0 * c0 - v2 * s0);
      op[1 * 16 + q16] = (bf16)(v1 * c1 - v3 * s1);
      op[2 * 16 + q16] = (bf16)(v2 * c0 + v0 * s0);
      op[3 * 16 + q16] = (bf16)(v3 * c1 + v1 * s1);
    }
  } else {
    // V path: LDS transpose -> vt[((b*4+vh)*64+d)*2048 + t]
    const int vh = (n0 - 256) >> 6;
    const int b = m0 >> 11;
    const int tblk = m0 & 2047;
#pragma unroll
    for (int nt = 0; nt < 4; ++nt)
#pragma unroll
      for (int r = 0; r < 4; ++r)
        As[wave * 16 + quad * 4 + r][nt * 16 + q16] = (bf16)acc[nt][r];
    __syncthreads();
#pragma unroll
    for (int rep = 0; rep < 2; ++rep) {
      int c = tid + 256 * rep;
      int d = c >> 3;
      int t8 = (c & 7) * 8;
      bf16x8 pk;
#pragma unroll
      for (int j = 0; j < 8; ++j) pk[j] = As[t8 + j][d];
      *(bf16x8*)&vt[(((size_t)(b * 4 + vh)) * 64 + d) * 2048 + tblk + t8] = pk;
    }
  }
}

// ---------------------------------------------------------------------------
// o-projection: 128x128-tile GEMM, output dtype per detected input dtype.
// ---------------------------------------------------------------------------
__global__ __launch_bounds__(256) void gemm_o_kernel(
    const bf16* __restrict__ A, const bf16* __restrict__ W,
    void* __restrict__ C, int K, const unsigned short* __restrict__ cosRaw) {
  __shared__ bf16 As[128 * 64];
  __shared__ bf16 Bs[128 * 64];

  const int n0 = blockIdx.x * 128;
  const int m0 = blockIdx.y * 128;
  const int tid = threadIdx.x;
  const int wave = tid >> 6;
  const int lane = tid & 63;
  const int q16 = lane & 15;
  const int quad = lane >> 4;
  const int srow = lane >> 3;
  const int csrc = (lane & 7) ^ srow;
  const int wm = (wave >> 1) * 64;
  const int wn = (wave & 1) * 64;
  const int x7 = q16 & 7;
  const bool bfout = is_bf16_input(cosRaw);

  f32x4 acc[4][4];
#pragma unroll
  for (int mt = 0; mt < 4; ++mt)
#pragma unroll
    for (int nt = 0; nt < 4; ++nt) acc[mt][nt] = (f32x4){0.f, 0.f, 0.f, 0.f};

  for (int ko = 0; ko < K; ko += 64) {
    __syncthreads();
#pragma unroll
    for (int i = 0; i < 4; ++i) {
      int rb = wave * 32 + i * 8;
      GLOAD_LDS16(&A[(size_t)(m0 + rb + srow) * K + ko + csrc * 8], &As[rb * 64]);
      GLOAD_LDS16(&W[(size_t)(n0 + rb + srow) * K + ko + csrc * 8], &Bs[rb * 64]);
    }
    __syncthreads();

    bf16x8 af[4][2], bfr[4][2];
#pragma unroll
    for (int mt = 0; mt < 4; ++mt) {
      const bf16* rp = &As[(wm + mt * 16 + q16) * 64];
      af[mt][0] = *(const bf16x8*)&rp[(quad ^ x7) * 8];
      af[mt][1] = *(const bf16x8*)&rp[((quad + 4) ^ x7) * 8];
    }
#pragma unroll
    for (int nt = 0; nt < 4; ++nt) {
      const bf16* rp = &Bs[(wn + nt * 16 + q16) * 64];
      bfr[nt][0] = *(const bf16x8*)&rp[(quad ^ x7) * 8];
      bfr[nt][1] = *(const bf16x8*)&rp[((quad + 4) ^ x7) * 8];
    }
#pragma unroll
    for (int mt = 0; mt < 4; ++mt)
#pragma unroll
      for (int nt = 0; nt < 4; ++nt) {
        acc[mt][nt] = MFMA(af[mt][0], bfr[nt][0], acc[mt][nt]);
        acc[mt][nt] = MFMA(af[mt][1], bfr[nt][1], acc[mt][nt]);
      }
  }

#pragma unroll
  for (int mt = 0; mt < 4; ++mt)
#pragma unroll
    for (int nt = 0; nt < 4; ++nt)
#pragma unroll
      for (int r = 0; r < 4; ++r) {
        size_t idx = (size_t)(m0 + wm + mt * 16 + quad * 4 + r) * 1024 +
                     n0 + wn + nt * 16 + q16;
        if (bfout) ((bf16*)C)[idx] = (bf16)acc[mt][nt][r];
        else       ((float*)C)[idx] = acc[mt][nt][r];
      }
}

// ---------------------------------------------------------------------------
// Flash attention v5 (round-5 version, unchanged): 4 waves/block, 64 queries,
// fixed-max softmax exp(S-9), l via ones-MFMA, K/V LDS dbuf, LB swizzle.
// ---------------------------------------------------------------------------
__global__ __launch_bounds__(256, 4) void flash_kernel(
    const bf16* __restrict__ qp, const bf16* __restrict__ kp,
    const bf16* __restrict__ vt, bf16* __restrict__ attn) {
  const int qblk = (31 - (int)blockIdx.x + (int)blockIdx.y + 16 * (int)blockIdx.z) & 31;
  const int h = blockIdx.y;
  const int b = blockIdx.z;
  const int kvh = h >> 2;
  const int tid = threadIdx.x;
  const int wave = tid >> 6;
  const int lane = tid & 63;
  const int q16 = lane & 15;
  const int quad = lane >> 4;
  const int r7 = q16 & 7;
  const int t0 = qblk * 64 + wave * 16;

  __shared__ bf16 Ks[2][64 * 64];
  __shared__ bf16 Vs[2][64 * 64];
  __shared__ bf16 Pl[4][16 * 64];

  const bf16* qrow = qp + (((size_t)(b * 2048 + t0 + q16)) * 16 + h) * 64;
  bf16x8 qa0 = *(const bf16x8*)(qrow + quad * 8);
  bf16x8 qa1 = *(const bf16x8*)(qrow + 32 + quad * 8);

  bf16x8 ones;
#pragma unroll
  for (int j = 0; j < 8; ++j) ones[j] = (bf16)1.0f;

  f32x4 O[4], l4;
#pragma unroll
  for (int nt = 0; nt < 4; ++nt) O[nt] = (f32x4){0.f, 0.f, 0.f, 0.f};
  l4 = (f32x4){0.f, 0.f, 0.f, 0.f};

  const int ntile = qblk + 1;

  bf16x8 kr[2], vr[2];
  const int cr = tid * 2;
  const int krow = cr >> 3;
  const size_t kgbase = (((size_t)(b * 2048) + krow) * 4 + kvh) * 64;
  const size_t vgbase = ((size_t)(b * 4 + kvh) * 64 + krow) * 2048;

  auto gload = [&](int tk) {
#pragma unroll
    for (int rep = 0; rep < 2; ++rep) {
      int ch = (cr + rep) & 7;
      kr[rep] = *(const bf16x8*)&kp[kgbase + (size_t)(tk * 64) * 256 + ch * 8];
      vr[rep] = *(const bf16x8*)&vt[vgbase + tk * 64 + ch * 8];
    }
  };
  auto swrite = [&](int bb) {
#pragma unroll
    for (int rep = 0; rep < 2; ++rep) {
      int ch = (cr + rep) & 7;
      int pos = (ch ^ (krow & 7)) * 8;
      *(bf16x8*)&Ks[bb][krow * 64 + pos] = kr[rep];
      *(bf16x8*)&Vs[bb][krow * 64 + pos] = vr[rep];
    }
  };

  gload(0);

  for (int t = 0; t < ntile; ++t) {
    const int bb = t & 1;
    const int kbase = t * 64;
    swrite(bb);
    __syncthreads();
    if (t + 1 < ntile) gload(t + 1);

    f32x4 s[4];
#pragma unroll
    for (int kt = 0; kt < 4; ++kt) {
      const bf16* kr0 = &Ks[bb][(kt * 16 + q16) * 64];
      bf16x8 kb0 = *(const bf16x8*)&kr0[(quad ^ r7) * 8];
      bf16x8 kb1 = *(const bf16x8*)&kr0[((quad + 4) ^ r7) * 8];
      f32x4 z = (f32x4){0.f, 0.f, 0.f, 0.f};
      z = MFMA(qa0, kb0, z);
      z = MFMA(qa1, kb1, z);
      s[kt] = z;
    }

    if (kbase + 63 > t0) {
#pragma unroll
      for (int kt = 0; kt < 4; ++kt) {
        int jt = kbase + kt * 16 + q16;
#pragma unroll
        for (int r = 0; r < 4; ++r)
          if (jt > t0 + quad * 4 + r) s[kt][r] = -1e30f;
      }
    }

#pragma unroll
    for (int kt = 0; kt < 4; ++kt)
#pragma unroll
      for (int r = 0; r < 4; ++r) s[kt][r] = __expf(s[kt][r] - 9.0f);

#pragma unroll
    for (int kt = 0; kt < 4; ++kt)
#pragma unroll
      for (int r = 0; r < 4; ++r) {
        int row = quad * 4 + r;
        int col = kt * 16 + q16;
        Pl[wave][row * 64 + ((col >> 3) ^ (row & 7)) * 8 + (col & 7)] =
            (bf16)s[kt][r];
      }

#pragma unroll
    for (int kh = 0; kh < 2; ++kh) {
      bf16x8 pa = *(const bf16x8*)&Pl[wave][q16 * 64 +
                                           (((kh * 4 + quad) ^ r7) * 8)];
#pragma unroll
      for (int nt = 0; nt < 4; ++nt) {
        const bf16* vr0 = &Vs[bb][(nt * 16 + q16) * 64];
        bf16x8 vb = *(const bf16x8*)&vr0[((kh * 4 + quad) ^ r7) * 8];
        O[nt] = MFMA(pa, vb, O[nt]);
      }
      l4 = MFMA(pa, ones, l4);
    }
  }

  float inv[4];
#pragma unroll
  for (int r = 0; r < 4; ++r) inv[r] = 1.0f / l4[r];
#pragma unroll
  for (int nt = 0; nt < 4; ++nt)
#pragma unroll
    for (int r = 0; r < 4; ++r) {
      size_t o = (((size_t)(b * 2048 + t0 + quad * 4 + r)) * 16 + h) * 64 +
                 nt * 16 + q16;
      attn[o] = (bf16)(O[nt][r] * inv[r]);
    }
}

// ---------------------------------------------------------------------------
extern "C" void kernel_launch(void* const* d_in, const int* in_sizes, int n_in,
                              void* d_out, int out_size, void* d_ws, size_t ws_size,
                              hipStream_t stream) {
  bf16* xc  = (bf16*)d_ws;                   // aliased as `at` after last use
  bf16* qp  = xc  + (size_t)4096 * 1024;
  bf16* kp  = qp  + (size_t)4096 * 1024;
  bf16* vt  = kp  + (size_t)4096 * 256;
  bf16* wqc = vt  + (size_t)4096 * 256;
  bf16* wkc = wqc + (size_t)1024 * 1024;     // wk rows then wv rows (contig)
  bf16* wvc = wkc + (size_t)256 * 1024;
  bf16* woc = wvc + (size_t)256 * 1024;
  bf16* csc = woc + (size_t)1024 * 1024;
  bf16* snc = csc + (size_t)2048 * 32;
  bf16* qnc = snc + (size_t)2048 * 32;
  bf16* knc = qnc + 64;
  bf16* at  = xc;
  const unsigned short* cosRaw = (const unsigned short*)d_in[1];

  // 1) fused converts
  CvArgs cva;
  const void* srcs[9] = {d_in[0], d_in[3], d_in[4], d_in[5], d_in[6],
                         d_in[1], d_in[2], d_in[7], d_in[8]};
  bf16* dsts[9] = {xc, wqc, wkc, wvc, woc, csc, snc, qnc, knc};
  int lens[9] = {4096 * 1024, 1024 * 1024, 256 * 1024, 256 * 1024, 1024 * 1024,
                 2048 * 32, 2048 * 32, 64, 64};
  int acc = 0;
  for (int i = 0; i < 9; ++i) {
    cva.src[i] = srcs[i];
    cva.dst[i] = dsts[i];
    acc += lens[i];
    cva.end[i] = acc;
  }
  convert_all_kernel<<<(acc / 8 + 255) / 256, 256, 0, stream>>>(cva, cosRaw);

  // 2) q projection + RMSNorm + RoPE + 1/8 scale
  gemm_q_kernel<<<dim3(8, 32), 256, 0, stream>>>(xc, wqc, qp, csc, snc, qnc, 1024);

  // 3) k+v projection (+ k norm/rope, + v transpose)
  gemm_kv_kernel<<<dim3(8, 64), 256, 0, stream>>>(xc, wkc, kp, vt, csc, snc, knc, 1024);

  // 4) causal GQA flash attention (writes at = xc alias)
  flash_kernel<<<dim3(32, 16, 2), 256, 0, stream>>>(qp, kp, vt, at);

  // 5) output projection -> d_out (dtype per detected input dtype)
  gemm_o_kernel<<<dim3(8, 32), 256, 0, stream>>>(at, woc, d_out, 1024, cosRaw);
}